// Round 15
// baseline (1140.609 us; speedup 1.0000x reference)
//
#include <hip/hip_runtime.h>
#include <cstdint>
#include <cstddef>

using bf16 = __bf16;
using f16  = _Float16;
typedef float f32x4 __attribute__((ext_vector_type(4)));
typedef bf16 bf16x8 __attribute__((ext_vector_type(8)));
typedef bf16 bf16x4 __attribute__((ext_vector_type(4)));
typedef f16  f16x8  __attribute__((ext_vector_type(8)));
typedef f16  f16x4  __attribute__((ext_vector_type(4)));

#define NB 4           // batch
#define SEQ 2048
#define DM 1024        // d_model
#define HD 4096        // hidden
#define SD (SEQ*DM)    // 2^21 elems per sample

__device__ __forceinline__ float geluf(float v) {
    return 0.5f * v * (1.0f + erff(v * 0.70710678118654752f));
}

#define GLL(gp, lp) __builtin_amdgcn_global_load_lds( \
    (const __attribute__((address_space(1))) void*)(gp), \
    (__attribute__((address_space(3))) void*)(lp), 16, 0, 0)

// ---------------------------------------------------------------------------
// Precision-tiered NT GEMM (proven single-buffer structure + block swizzle):
//   NP=3 (DT=0): C = Ah*Bh + Al*Bh + Ah*Bl  (split bf16, ~17-bit mantissa)
//   NP=1, DT=0 : C = Ah*Bh                  (plain bf16)
//   NP=1, DT=1 : C = A*B with fp16 operands (10-bit mantissa, 1 pass)
// EPI: 0 = f32 (+bias), 1 = f32 gelu (+bias), 4 = split bf16 store,
//      6 = fp16 store, 7 = fp16 transposed store
// ---------------------------------------------------------------------------
template<int EPI, bool BIAS, int NP, int DT>
__global__ __launch_bounds__(256, NP == 1 ? 4 : 2) void gemm3_nt(
    const bf16* __restrict__ Ah, const bf16* __restrict__ Al,
    const bf16* __restrict__ Bh, const bf16* __restrict__ Bl,
    const float* __restrict__ bias, void* __restrict__ Cg, void* __restrict__ Cl,
    const int K, const int ldab, const int ldc,
    const long sA, const long sB, const long sC)
{
    constexpr int TILE = 128 * 64;                 // elems per plane
    constexpr int LOSZ = (NP == 3) ? TILE : 8;     // lo planes only for NP=3
    __shared__ __align__(16) bf16 smAh[TILE];
    __shared__ __align__(16) bf16 smBh[TILE];
    __shared__ __align__(16) bf16 smAl[LOSZ];
    __shared__ __align__(16) bf16 smBl[LOSZ];

    const int tid  = threadIdx.x;
    const int lane = tid & 63;
    const int wave = tid >> 6;
    const int wr   = (wave >> 1) << 6;
    const int wc   = (wave & 1) << 6;
    const int l15  = lane & 15;
    const int q4   = lane >> 4;

    // ---- block swizzle: XCD chunk + 4x4 output supertile (bijective) ----
    int bx = blockIdx.x, by = blockIdx.y;
    {
        const int gx = gridDim.x, gy = gridDim.y;
        if (((gx & 3) | (gy & 3)) == 0) {
            const int tot = gx * gy;               // multiple of 16
            const int n   = bx + gx * by;
            const int l   = (n & 7) * (tot >> 3) + (n >> 3);   // XCD chunk
            const int st  = l >> 4, pos = l & 15;              // supertile
            bx = (st % (gx >> 2)) * 4 + (pos & 3);
            by = (st / (gx >> 2)) * 4 + (pos >> 2);
        }
    }

    const long aoff = (long)blockIdx.z * sA + (long)bx * 128 * ldab;
    const long boff = (long)blockIdx.z * sB + (long)by * 128 * ldab;
    const bf16* pAh = Ah + aoff;
    const bf16* pAl = (NP == 3) ? Al + aoff : nullptr;
    const bf16* pBh = Bh + boff;
    const bf16* pBl = (NP == 3) ? Bl + boff : nullptr;

    int srow[4], scol[4];
#pragma unroll
    for (int it = 0; it < 4; ++it) {
        int chunk = it * 256 + tid;
        int m = chunk >> 3;
        srow[it] = m;
        scol[it] = ((chunk & 7) ^ (m & 7)) * 8;
    }

    f32x4 acc[4][4] = {};

    for (int k0 = 0; k0 < K; k0 += 64) {
#pragma unroll
        for (int it = 0; it < 4; ++it) {
            const long go = (long)srow[it] * ldab + (k0 + scol[it]);
            const size_t lo = (size_t)(it * 256 + (wave << 6)) * 8;   // linear fill
            GLL(pAh + go, smAh + lo);
            if constexpr (NP == 3) GLL(pAl + go, smAl + lo);
            GLL(pBh + go, smBh + lo);
            if constexpr (NP == 3) GLL(pBl + go, smBl + lo);
        }
        __syncthreads();

#pragma unroll
        for (int kk = 0; kk < 2; ++kk) {
            bf16x8 avh[4], avl[4], bvh[4], bvl[4];
#pragma unroll
            for (int i = 0; i < 4; ++i) {
                const int rowa = wr + i * 16 + l15;
                const int ca = ((kk * 4 + q4) ^ (rowa & 7)) * 8;   // swizzled read
                avh[i] = *(const bf16x8*)(smAh + rowa * 64 + ca);
                if constexpr (NP == 3) avl[i] = *(const bf16x8*)(smAl + rowa * 64 + ca);
                const int rowb = wc + i * 16 + l15;
                const int cb = ((kk * 4 + q4) ^ (rowb & 7)) * 8;
                bvh[i] = *(const bf16x8*)(smBh + rowb * 64 + cb);
                if constexpr (NP == 3) bvl[i] = *(const bf16x8*)(smBl + rowb * 64 + cb);
            }
#pragma unroll
            for (int i = 0; i < 4; ++i)
#pragma unroll
                for (int j = 0; j < 4; ++j) {
                    if constexpr (DT == 1) {
                        acc[i][j] = __builtin_amdgcn_mfma_f32_16x16x32_f16(
                            *(const f16x8*)&avh[i], *(const f16x8*)&bvh[j],
                            acc[i][j], 0, 0, 0);
                    } else {
                        acc[i][j] = __builtin_amdgcn_mfma_f32_16x16x32_bf16(
                            avh[i], bvh[j], acc[i][j], 0, 0, 0);
                        if constexpr (NP == 3) {
                            acc[i][j] = __builtin_amdgcn_mfma_f32_16x16x32_bf16(
                                avl[i], bvh[j], acc[i][j], 0, 0, 0);
                            acc[i][j] = __builtin_amdgcn_mfma_f32_16x16x32_bf16(
                                avh[i], bvl[j], acc[i][j], 0, 0, 0);
                        }
                    }
                }
        }
        __syncthreads();
    }

    // epilogue: D col = lane&15, row = (lane>>4)*4 + e
    const long zC = (long)blockIdx.z * sC;
    const int gcol0 = by * 128 + wc + l15;
    const int grow0 = bx * 128 + wr + q4 * 4;
#pragma unroll
    for (int j = 0; j < 4; ++j) {
        const int col = gcol0 + j * 16;
        const float bvz = BIAS ? bias[col] : 0.0f;
#pragma unroll
        for (int i = 0; i < 4; ++i) {
            const int row = grow0 + i * 16;
            if (EPI == 7) {
                f16x4 o;
#pragma unroll
                for (int e = 0; e < 4; ++e) o[e] = (f16)(acc[i][j][e] + bvz);
                *(f16x4*)((f16*)Cg + zC + (long)col * ldc + row) = o;
            } else {
#pragma unroll
                for (int e = 0; e < 4; ++e) {
                    float v = acc[i][j][e] + bvz;
                    if (EPI == 1) v = geluf(v);
                    const long off = zC + (long)(row + e) * ldc + col;
                    if (EPI == 4) {
                        const bf16 hi = (bf16)v;
                        ((bf16*)Cg)[off] = hi;
                        ((bf16*)Cl)[off] = (bf16)(v - (float)hi);
                    } else if (EPI == 6) {
                        ((f16*)Cg)[off] = (f16)v;
                    } else {
                        ((float*)Cg)[off] = v;
                    }
                }
            }
        }
    }
}

// ---------------------------------------------------------------------------
// y = emb[x] + pos -> split bf16 + fp16 plane; vbias row-dot
// ---------------------------------------------------------------------------
__global__ __launch_bounds__(256) void embed_k(
    const int* __restrict__ x, const float* __restrict__ emb,
    bf16* __restrict__ yh, bf16* __restrict__ yl, f16* __restrict__ yf16,
    const float* __restrict__ wkbq, float* __restrict__ vb)
{
    const int bs = blockIdx.x;          // row
    const int s = bs & (SEQ - 1);
    const long e0 = (long)x[bs] * DM;
    const int d = threadIdx.x * 4;
    const float4 ev = *(const float4*)(emb + e0 + d);
    float o[4];
    const float fs = (float)s;
#pragma unroll
    for (int e = 0; e < 4; ++e) {
        const int dd = d + e;
        const float div = powf(10000.0f, (float)dd * (1.0f / 1024.0f));
        const float ang = fs / div;
        const float p = (dd & 1) ? cosf(ang) : sinf(ang);
        o[e] = ((const float*)&ev)[e] + p;
    }
    bf16x4 oh, ol; f16x4 of;
#pragma unroll
    for (int e = 0; e < 4; ++e) {
        oh[e] = (bf16)o[e];
        ol[e] = (bf16)(o[e] - (float)oh[e]);
        of[e] = (f16)o[e];
    }
    *(bf16x4*)(yh + (long)bs * DM + d) = oh;
    *(bf16x4*)(yl + (long)bs * DM + d) = ol;
    *(f16x4*) (yf16 + (long)bs * DM + d) = of;
    const float4 wv = *(const float4*)(wkbq + d);
    float sdot = o[0] * wv.x + o[1] * wv.y + o[2] * wv.z + o[3] * wv.w;
#pragma unroll
    for (int off = 32; off; off >>= 1) sdot += __shfl_xor(sdot, off);
    __shared__ float red[4];
    if ((threadIdx.x & 63) == 0) red[threadIdx.x >> 6] = sdot;
    __syncthreads();
    if (threadIdx.x == 0) vb[bs] = red[0] + red[1] + red[2] + red[3];
}

// ---------------------------------------------------------------------------
// f32 -> split bf16 straight copy (layer-0 score weights)
// ---------------------------------------------------------------------------
__global__ __launch_bounds__(256) void copy_split_k(
    const float* __restrict__ src, bf16* __restrict__ dh, bf16* __restrict__ dl)
{
    const long i = ((long)blockIdx.x * 256 + threadIdx.x) * 4;
    const float4 v = *(const float4*)(src + i);
    const float vv[4] = {v.x, v.y, v.z, v.w};
    bf16x4 oh, ol;
#pragma unroll
    for (int e = 0; e < 4; ++e) {
        const bf16 hi = (bf16)vv[e];
        oh[e] = hi;
        ol[e] = (bf16)(vv[e] - (float)hi);
    }
    *(bf16x4*)(dh + i) = oh;
    *(bf16x4*)(dl + i) = ol;
}

// ---------------------------------------------------------------------------
// f32 -> f16 straight copy
// ---------------------------------------------------------------------------
__global__ __launch_bounds__(256) void copy_f16_k(
    const float* __restrict__ src, f16* __restrict__ dst)
{
    const long i = ((long)blockIdx.x * 256 + threadIdx.x) * 4;
    const float4 v = *(const float4*)(src + i);
    f16x4 o;
    o[0] = (f16)v.x; o[1] = (f16)v.y; o[2] = (f16)v.z; o[3] = (f16)v.w;
    *(f16x4*)(dst + i) = o;
}

// ---------------------------------------------------------------------------
// f32 R x C -> f16 C x R transpose
// ---------------------------------------------------------------------------
__global__ __launch_bounds__(256) void transpose_f16_k(
    const float* __restrict__ src, f16* __restrict__ dst, int R, int C)
{
    __shared__ f16 tf[64][65];
    const int c0 = blockIdx.x * 64, r0 = blockIdx.y * 64;
    const int t = threadIdx.x;
    const int tr = t >> 4;
    const int tc = (t & 15) * 4;
#pragma unroll
    for (int p = 0; p < 4; ++p) {
        const int r = tr + p * 16;
        const float4 v = *(const float4*)(src + (long)(r0 + r) * C + c0 + tc);
        tf[r][tc] = (f16)v.x; tf[r][tc + 1] = (f16)v.y;
        tf[r][tc + 2] = (f16)v.z; tf[r][tc + 3] = (f16)v.w;
    }
    __syncthreads();
#pragma unroll
    for (int p = 0; p < 4; ++p) {
        const int c = tr + p * 16;
        f16x4 o;
        o[0] = tf[tc][c]; o[1] = tf[tc + 1][c]; o[2] = tf[tc + 2][c]; o[3] = tf[tc + 3][c];
        *(f16x4*)(dst + (long)(c0 + c) * R + r0 + tc) = o;
    }
}

// ---------------------------------------------------------------------------
// 8-plane f32 reduce -> split bf16 (straight, for MT layer 0)
// ---------------------------------------------------------------------------
__global__ __launch_bounds__(256) void reduce8s_k(
    const float* __restrict__ p, bf16* __restrict__ dh, bf16* __restrict__ dl)
{
    const long i = ((long)blockIdx.x * 256 + threadIdx.x) * 4;
    const long PL = (long)1 << 20;
    float vv[4] = {0.f, 0.f, 0.f, 0.f};
#pragma unroll
    for (int q = 0; q < 8; ++q) {
        const float4 a = *(const float4*)(p + q * PL + i);
        vv[0] += a.x; vv[1] += a.y; vv[2] += a.z; vv[3] += a.w;
    }
    bf16x4 oh, ol;
#pragma unroll
    for (int e = 0; e < 4; ++e) {
        const bf16 hi = (bf16)vv[e];
        oh[e] = hi;
        ol[e] = (bf16)(vv[e] - (float)hi);
    }
    *(bf16x4*)(dh + i) = oh;
    *(bf16x4*)(dl + i) = ol;
}

// ---------------------------------------------------------------------------
// wb[d] = sum_h W[d][h] * b[h]   (f32, W is [1024][4096])
// ---------------------------------------------------------------------------
__global__ __launch_bounds__(256) void matvec_wb_k(
    const float* __restrict__ W, const float* __restrict__ b, float* __restrict__ out)
{
    const int d = blockIdx.x;
    const int t = threadIdx.x;
    float s = 0.f;
    for (int h = t * 4; h < HD; h += 1024) {
        const float4 wv = *(const float4*)(W + (long)d * HD + h);
        const float4 bv = *(const float4*)(b + h);
        s += wv.x * bv.x + wv.y * bv.y + wv.z * bv.z + wv.w * bv.w;
    }
#pragma unroll
    for (int o = 32; o; o >>= 1) s += __shfl_xor(s, o);
    __shared__ float red[4];
    if ((t & 63) == 0) red[t >> 6] = s;
    __syncthreads();
    if (t == 0) out[d] = red[0] + red[1] + red[2] + red[3];
}

// ---------------------------------------------------------------------------
// out[j] = sum_h Btf[j][h] * b[h] + add[j]   (Btf is f16 [1024][4096])
// ---------------------------------------------------------------------------
__global__ __launch_bounds__(256) void matvec_btf_k(
    const f16* __restrict__ btf, const float* __restrict__ b,
    const float* __restrict__ add, float* __restrict__ out)
{
    const int j = blockIdx.x;
    const int t = threadIdx.x;
    float s = 0.f;
    for (int h = t * 4; h < HD; h += 1024) {
        const f16x4 hx = *(const f16x4*)(btf + (long)j * HD + h);
        const float4 bv = *(const float4*)(b + h);
        s += (float)hx[0] * bv.x + (float)hx[1] * bv.y
           + (float)hx[2] * bv.z + (float)hx[3] * bv.w;
    }
#pragma unroll
    for (int o = 32; o; o >>= 1) s += __shfl_xor(s, o);
    __shared__ float red[4];
    if ((t & 63) == 0) red[t >> 6] = s;
    __syncthreads();
    if (t == 0) out[j] = red[0] + red[1] + red[2] + red[3] + add[j];
}

// ---------------------------------------------------------------------------
// Row softmax with key-side column bias -> fp16 P
// ---------------------------------------------------------------------------
__global__ __launch_bounds__(256) void softmax_k(
    const float* __restrict__ S, const float* __restrict__ v,
    f16* __restrict__ P)
{
    const long row = blockIdx.x;
    const float4* src = (const float4*)(S + (row << 11));
    const float* vr = v + (long)(row >> 11) * SEQ;
    const int t = threadIdx.x;
    float4 a = src[t], b = src[256 + t];
    const float4 va = *(const float4*)(vr + t * 4);
    const float4 vb = *(const float4*)(vr + 1024 + t * 4);
    a.x += va.x; a.y += va.y; a.z += va.z; a.w += va.w;
    b.x += vb.x; b.y += vb.y; b.z += vb.z; b.w += vb.w;
    float m = fmaxf(fmaxf(fmaxf(a.x, a.y), fmaxf(a.z, a.w)),
                    fmaxf(fmaxf(b.x, b.y), fmaxf(b.z, b.w)));
#pragma unroll
    for (int o = 32; o; o >>= 1) m = fmaxf(m, __shfl_xor(m, o));
    __shared__ float red1[4], red2[4];
    const int wv = t >> 6;
    if ((t & 63) == 0) red1[wv] = m;
    __syncthreads();
    m = fmaxf(fmaxf(red1[0], red1[1]), fmaxf(red1[2], red1[3]));

    a.x = expf(a.x - m); a.y = expf(a.y - m); a.z = expf(a.z - m); a.w = expf(a.w - m);
    b.x = expf(b.x - m); b.y = expf(b.y - m); b.z = expf(b.z - m); b.w = expf(b.w - m);
    float s = a.x + a.y + a.z + a.w + b.x + b.y + b.z + b.w;
#pragma unroll
    for (int o = 32; o; o >>= 1) s += __shfl_xor(s, o);
    if ((t & 63) == 0) red2[wv] = s;
    __syncthreads();
    s = red2[0] + red2[1] + red2[2] + red2[3];
    const float inv = 1.0f / s;

    f16x4 o0, o1;
    o0[0] = (f16)(a.x * inv); o0[1] = (f16)(a.y * inv);
    o0[2] = (f16)(a.z * inv); o0[3] = (f16)(a.w * inv);
    o1[0] = (f16)(b.x * inv); o1[1] = (f16)(b.y * inv);
    o1[2] = (f16)(b.z * inv); o1[3] = (f16)(b.w * inv);
    *(f16x4*)(P + (row << 11) + t * 4) = o0;
    *(f16x4*)(P + (row << 11) + 1024 + t * 4) = o1;
}

// ---------------------------------------------------------------------------
// LayerNorm over whole (S,D) sample; residual carried as split bf16 (hi+lo).
// ---------------------------------------------------------------------------
__global__ __launch_bounds__(256) void ln_stats_k(
    const bf16* __restrict__ yh, const bf16* __restrict__ yl,
    const float* __restrict__ r, float2* __restrict__ part)
{
    const int b = blockIdx.y;
    const long base = (long)b * SD + (long)blockIdx.x * (SD / 64);
    float s = 0.f, q = 0.f;
    for (int i = threadIdx.x; i < (SD / 64) / 4; i += 256) {
        const bf16x4 h = *(const bf16x4*)(yh + base + i * 4);
        const bf16x4 l = *(const bf16x4*)(yl + base + i * 4);
        const float4 c = *(const float4*)(r + base + i * 4);
        const float cc[4] = {c.x, c.y, c.z, c.w};
#pragma unroll
        for (int e = 0; e < 4; ++e) {
            const float xx = (float)h[e] + (float)l[e] + cc[e];
            s += xx; q += xx * xx;
        }
    }
#pragma unroll
    for (int o = 32; o; o >>= 1) { s += __shfl_xor(s, o); q += __shfl_xor(q, o); }
    __shared__ float rs[4], rq[4];
    const int wv = threadIdx.x >> 6;
    if ((threadIdx.x & 63) == 0) { rs[wv] = s; rq[wv] = q; }
    __syncthreads();
    if (threadIdx.x == 0)
        part[b * 64 + blockIdx.x] = make_float2(rs[0] + rs[1] + rs[2] + rs[3],
                                                rq[0] + rq[1] + rq[2] + rq[3]);
}

__global__ void ln_fin_k(const float2* __restrict__ part, float2* __restrict__ stats)
{
    const int b = blockIdx.x;
    const float2 p = part[b * 64 + threadIdx.x];
    float s = p.x, q = p.y;
#pragma unroll
    for (int o = 32; o; o >>= 1) { s += __shfl_xor(s, o); q += __shfl_xor(q, o); }
    if (threadIdx.x == 0) {
        const float inv_n = 1.0f / (float)SD;
        const float mean = s * inv_n;
        const float var = fmaxf(q * inv_n - mean * mean, 0.f);
        stats[b] = make_float2(mean, rsqrtf(var + 1e-5f));
    }
}

// ln_apply: one block per row; writes split bf16 + fp16 (+f32 out),
// optionally next layer's vbias row-dot.
__global__ __launch_bounds__(256) void ln_apply_k(
    const bf16* __restrict__ yh_in, const bf16* __restrict__ yl_in,
    const float* __restrict__ r,
    const float* __restrict__ w, const float* __restrict__ bb,
    const float2* __restrict__ stats,
    bf16* __restrict__ yh_out, bf16* __restrict__ yl_out, f16* __restrict__ yf16,
    float* __restrict__ fout,
    const float* __restrict__ wkbq, float* __restrict__ vb)
{
    const long i = (long)blockIdx.x * 1024 + threadIdx.x * 4;
    const int smp = (int)(i >> 21);
    const long sd = i & (SD - 1);
    const float2 st = stats[smp];
    const bf16x4 h = *(const bf16x4*)(yh_in + i);
    const bf16x4 l = *(const bf16x4*)(yl_in + i);
    const float4 c = *(const float4*)(r + i);
    const float4 wv = *(const float4*)(w + sd);
    const float4 bv = *(const float4*)(bb + sd);
    const float cc[4] = {c.x, c.y, c.z, c.w};
    const float ww[4] = {wv.x, wv.y, wv.z, wv.w};
    const float bbx[4] = {bv.x, bv.y, bv.z, bv.w};
    float o[4];
#pragma unroll
    for (int e = 0; e < 4; ++e) {
        const float xx = (float)h[e] + (float)l[e] + cc[e];
        o[e] = (xx - st.x) * st.y * ww[e] + bbx[e];
    }
    bf16x4 oh, ol; f16x4 of;
#pragma unroll
    for (int e = 0; e < 4; ++e) {
        oh[e] = (bf16)o[e];
        ol[e] = (bf16)(o[e] - (float)oh[e]);
        of[e] = (f16)o[e];
    }
    *(bf16x4*)(yh_out + i) = oh;
    *(bf16x4*)(yl_out + i) = ol;
    *(f16x4*) (yf16 + i) = of;
    if (fout != nullptr) *(float4*)(fout + i) = *(float4*)o;
    if (vb != nullptr) {
        const int d = threadIdx.x * 4;
        const float4 kv = *(const float4*)(wkbq + d);
        float sdot = o[0] * kv.x + o[1] * kv.y + o[2] * kv.z + o[3] * kv.w;
#pragma unroll
        for (int off = 32; off; off >>= 1) sdot += __shfl_xor(sdot, off);
        __shared__ float red[4];
        if ((threadIdx.x & 63) == 0) red[threadIdx.x >> 6] = sdot;
        __syncthreads();
        if (threadIdx.x == 0) vb[blockIdx.x] = red[0] + red[1] + red[2] + red[3];
    }
}

// ---------------------------------------------------------------------------
extern "C" void kernel_launch(void* const* d_in, const int* in_sizes, int n_in,
                              void* d_out, int out_size, void* d_ws, size_t ws_size,
                              hipStream_t stream)
{
    (void)in_sizes; (void)n_in; (void)out_size; (void)ws_size;

    const int*   x    = (const int*)  d_in[0];
    const float* emb  = (const float*)d_in[1];
    const float* wq   = (const float*)d_in[2];
    const float* bq   = (const float*)d_in[3];
    const float* wk   = (const float*)d_in[4];
    const float* bk   = (const float*)d_in[5];
    const float* wv   = (const float*)d_in[6];
    const float* bv   = (const float*)d_in[7];
    const float* wo   = (const float*)d_in[8];
    const float* bo   = (const float*)d_in[9];
    const float* w1   = (const float*)d_in[10];
    const float* b1   = (const float*)d_in[11];
    const float* w2   = (const float*)d_in[12];
    const float* b2   = (const float*)d_in[13];
    const float* ln1w = (const float*)d_in[14];
    const float* ln1b = (const float*)d_in[15];
    const float* ln2w = (const float*)d_in[16];
    const float* ln2b = (const float*)d_in[17];
    (void)bk;   // cancels in softmax (row-constant)

    // Workspace — peak ~324 MiB (≤384 proven-safe).
    char* ws = (char*)d_ws;
    const size_t MB = (size_t)1 << 20;
    bf16*   ybh   = (bf16*) (ws);                  //  16 MiB residual hi
    bf16*   ybl   = (bf16*) (ws + 16  * MB);       //  16 MiB residual lo
    f16*    yf16  = (f16*)  (ws + 32  * MB);       //  16 MiB residual fp16
    bf16*   S0h   = (bf16*) (ws + 48  * MB);       //   8 MiB slot (bf16-split / f16 reuse)
    bf16*   S0l   = (bf16*) (ws + 56  * MB);       //   8 MiB
    bf16*   S1h   = (bf16*) (ws + 64  * MB);       //   8 MiB
    bf16*   S1l   = (bf16*) (ws + 72  * MB);       //   8 MiB
    f16*    F0    = (f16*)  (ws + 48  * MB);       //   8 MiB f16 view of S0h slot
    f16*    F1    = (f16*)  (ws + 56  * MB);       //   8 MiB f16 view of S0l slot
    bf16*   MTh   = (bf16*) (ws + 80  * MB);       //   2 MiB
    bf16*   MTl   = (bf16*) (ws + 82  * MB);       //   2 MiB
    f16*    MTf   = (f16*)  (ws + 84  * MB);       //   2 MiB
    f16*    VOTf  = (f16*)  (ws + 86  * MB);       //   2 MiB W_vo^T fp16
    f16*    W12Tf = (f16*)  (ws + 88  * MB);       //   2 MiB W_12^T fp16
    float*  wkbq2 = (float*)(ws + 90  * MB);                // 2 x 4 KiB
    float*  c_vo  = (float*)(ws + 90  * MB + 0x10000);      // 4 KiB
    float*  c_12  = (float*)(ws + 90  * MB + 0x20000);      // 4 KiB
    float*  vbias = (float*)(ws + 90  * MB + 0x30000);      // 32 KiB
    float2* part  = (float2*)(ws + 90 * MB + 0x40000);
    float2* stats = (float2*)(ws + 90 * MB + 0x50000);
    float*  wtmp8 = (float*)(ws + 92  * MB);       //  32 MiB K-split f32 partials (MT-l0)
    bf16*   zh    = (bf16*) (ws + 124 * MB);       //  16 MiB z hi [8192][1024]
    bf16*   zl    = (bf16*) (ws + 140 * MB);       //  16 MiB z lo
    f16*    zf    = (f16*)  (ws + 156 * MB);       //  16 MiB z fp16
    f16*    uTf   = (f16*)  (ws + 172 * MB);       //  16 MiB u^T fp16 [4][1024][2048]
    float*  scf   = (float*)(ws + 188 * MB);       //  64 MiB scores f32 [4][2048][2048]
    f16*    Pf    = (f16*)  (ws + 252 * MB);       //  32 MiB probs fp16
    float*  attout= (float*)(ws + 284 * MB);       //  32 MiB f32 [8192][1024]
    float*  ffnf  = attout;

    const long TSZ = (long)DM * HD;

    // key-side weight-bias vectors for both layers (weight-only)
    matvec_wb_k<<<1024, 256, 0, stream>>>(wk + 0 * TSZ, bq + 0 * HD, wkbq2);
    matvec_wb_k<<<1024, 256, 0, stream>>>(wk + 1 * TSZ, bq + 1 * HD, wkbq2 + 0x4000 / 4);

    embed_k<<<NB * SEQ, 256, 0, stream>>>(x, emb, ybh, ybl, yf16, wkbq2, vbias);

    for (int l = 0; l < 2; ++l) {
        const float* wkbq_next = wkbq2 + 0x4000 / 4;

        // ============ score path ============
        if (l == 0) {
            // strict NP=3 bf16-split (doubly softmax-amplified)
            copy_split_k<<<4096, 256, 0, stream>>>(wq + l * TSZ, S0h, S0l);
            copy_split_k<<<4096, 256, 0, stream>>>(wk + l * TSZ, S1h, S1l);
            gemm3_nt<0, false, 3, 0><<<dim3(8, 8, 8), 256, 0, stream>>>(
                S1h, S1l, S0h, S0l, nullptr, wtmp8, nullptr,
                512, HD, 1024, 512, 512, (long)1 << 20);
            reduce8s_k<<<1024, 256, 0, stream>>>(wtmp8, MTh, MTl);
            gemm3_nt<4, false, 3, 0><<<dim3(64, 8, 1), 256, 0, stream>>>(
                ybh, ybl, MTh, MTl, nullptr, zh, zl, DM, DM, DM, 0, 0, 0);
            gemm3_nt<0, false, 3, 0><<<dim3(16, 16, NB), 256, 0, stream>>>(
                zh, zl, ybh, ybl, nullptr, scf, nullptr,
                DM, DM, SEQ, (long)SD, (long)SD, (long)SEQ * SEQ);
        } else {
            // relaxed fp16: MT = Wk·Wq^T single-launch, then z, scores fp16
            copy_f16_k<<<4096, 256, 0, stream>>>(wq + l * TSZ, F0);
            copy_f16_k<<<4096, 256, 0, stream>>>(wk + l * TSZ, F1);
            gemm3_nt<6, false, 1, 1><<<dim3(8, 8, 1), 256, 0, stream>>>(
                (const bf16*)F1, nullptr, (const bf16*)F0, nullptr, nullptr,
                MTf, nullptr, HD, HD, DM, 0, 0, 0);
            gemm3_nt<6, false, 1, 1><<<dim3(64, 8, 1), 256, 0, stream>>>(
                (const bf16*)yf16, nullptr, (const bf16*)MTf, nullptr, nullptr,
                zf, nullptr, DM, DM, DM, 0, 0, 0);
            gemm3_nt<0, false, 1, 1><<<dim3(16, 16, NB), 256, 0, stream>>>(
                (const bf16*)zf, nullptr, (const bf16*)yf16, nullptr, nullptr,
                scf, nullptr, DM, DM, SEQ, (long)SD, (long)SD, (long)SEQ * SEQ);
        }
        softmax_k<<<NB * SEQ, 256, 0, stream>>>(scf, vbias, Pf);

        // ============ value path: VO^T = Wo^T · Wv^T (fp16 single-launch) ===
        f16* WvF  = (f16*)(ws + 64 * MB);   // reuse S1h slot (dead post-score)
        f16* WoTf = (f16*)(ws + 72 * MB);   // reuse S1l slot
        copy_f16_k     <<<4096, 256, 0, stream>>>(wv + l * TSZ, WvF);
        transpose_f16_k<<<dim3(16, 64), 256, 0, stream>>>(wo + l * TSZ, WoTf, HD, DM);
        matvec_btf_k<<<1024, 256, 0, stream>>>(WoTf, bv + l * HD, bo + l * DM, c_vo);
        gemm3_nt<6, false, 1, 1><<<dim3(8, 8, 1), 256, 0, stream>>>(
            (const bf16*)WoTf, nullptr, (const bf16*)WvF, nullptr, nullptr,
            VOTf, nullptr, HD, HD, DM, 0, 0, 0);
        // u^T = (y·W_vo)^T -> fp16 [4][1024][2048]
        gemm3_nt<7, false, 1, 1><<<dim3(16, 8, NB), 256, 0, stream>>>(
            (const bf16*)yf16, nullptr, (const bf16*)VOTf, nullptr, nullptr,
            uTf, nullptr, DM, DM, SEQ, (long)SD, 0, (long)DM * SEQ);
        // attout = P·u + c_vo
        gemm3_nt<0, true, 1, 1><<<dim3(16, 8, NB), 256, 0, stream>>>(
            (const bf16*)Pf, nullptr, (const bf16*)uTf, nullptr, c_vo, attout, nullptr,
            SEQ, SEQ, DM, (long)SEQ * SEQ, (long)DM * SEQ, (long)SEQ * DM);
        // LN1(y + attout)
        ln_stats_k<<<dim3(64, NB), 256, 0, stream>>>(ybh, ybl, attout, part);
        ln_fin_k  <<<NB, 64, 0, stream>>>(part, stats);
        ln_apply_k<<<8192, 256, 0, stream>>>(ybh, ybl, attout,
                                             ln1w + (long)l * SD, ln1b + (long)l * SD,
                                             stats, ybh, ybl, yf16, nullptr,
                                             nullptr, nullptr);

        // ============ FFN path: W12^T = W2^T · W1^T (exact collapse, fp16) ===
        f16* W1F  = (f16*)(ws + 48 * MB);   // reuse S0h slot
        f16* W2Tf = (f16*)(ws + 56 * MB);   // reuse S0l slot
        copy_f16_k     <<<4096, 256, 0, stream>>>(w1 + l * TSZ, W1F);
        transpose_f16_k<<<dim3(16, 64), 256, 0, stream>>>(w2 + l * TSZ, W2Tf, HD, DM);
        matvec_btf_k<<<1024, 256, 0, stream>>>(W2Tf, b1 + l * HD, b2 + l * DM, c_12);
        gemm3_nt<6, false, 1, 1><<<dim3(8, 8, 1), 256, 0, stream>>>(
            (const bf16*)W2Tf, nullptr, (const bf16*)W1F, nullptr, nullptr,
            W12Tf, nullptr, HD, HD, DM, 0, 0, 0);
        // ffn = gelu(y·W_12 + c_12)
        gemm3_nt<1, true, 1, 1><<<dim3(64, 8, 1), 256, 0, stream>>>(
            (const bf16*)yf16, nullptr, (const bf16*)W12Tf, nullptr, c_12,
            ffnf, nullptr, DM, DM, DM, 0, 0, 0);
        // LN2; layer-0 apply emits next layer's vbias; layer-1 writes d_out
        float* fdst = (l == 1) ? (float*)d_out : nullptr;
        ln_stats_k<<<dim3(64, NB), 256, 0, stream>>>(ybh, ybl, ffnf, part);
        ln_fin_k  <<<NB, 64, 0, stream>>>(part, stats);
        ln_apply_k<<<8192, 256, 0, stream>>>(ybh, ybl, ffnf,
                                             ln2w + (long)l * SD, ln2b + (long)l * SD,
                                             stats, ybh, ybl, yf16, fdst,
                                             (l == 0) ? wkbq_next : nullptr,
                                             (l == 0) ? vbias : nullptr);
    }
}

// Round 16
// 1018.393 us; speedup vs baseline: 1.1200x; 1.1200x over previous
//
#include <hip/hip_runtime.h>
#include <cstdint>
#include <cstddef>

using bf16 = __bf16;
using f16  = _Float16;
typedef float f32x4 __attribute__((ext_vector_type(4)));
typedef bf16 bf16x8 __attribute__((ext_vector_type(8)));
typedef bf16 bf16x4 __attribute__((ext_vector_type(4)));
typedef f16  f16x8  __attribute__((ext_vector_type(8)));
typedef f16  f16x4  __attribute__((ext_vector_type(4)));

#define NB 4           // batch
#define SEQ 2048
#define DM 1024        // d_model
#define HD 4096        // hidden
#define SD (SEQ*DM)    // 2^21 elems per sample

__device__ __forceinline__ float geluf(float v) {
    return 0.5f * v * (1.0f + erff(v * 0.70710678118654752f));
}

#define GLL(gp, lp) __builtin_amdgcn_global_load_lds( \
    (const __attribute__((address_space(1))) void*)(gp), \
    (__attribute__((address_space(3))) void*)(lp), 16, 0, 0)

// ---------------------------------------------------------------------------
// Precision-tiered NT GEMM (R10 proven single-buffer structure + R13 swizzle):
//   NP=3 (DT=0): C = Ah*Bh + Al*Bh + Ah*Bl  (split bf16, ~17-bit mantissa)
//   NP=1, DT=0 : C = Ah*Bh                  (plain bf16)
//   NP=1, DT=1 : C = A*B with fp16 operands (10-bit mantissa, 1 pass)
// A: M x K row-major (pair), Bt: N x K row-major (pair); 2-byte elements.
// ldab = row stride of A and B. Tile 128x128x64, 4 waves, 16x16x32 MFMA,
// global_load_lds staging, chunk XOR swizzle both-sides, 4x4-supertile/XCD
// block swizzle.
// EPI: 0 = f32 (+bias), 1 = f32 gelu (+bias), 4 = split bf16 store,
//      6 = fp16 store, 7 = fp16 transposed store
// ---------------------------------------------------------------------------
template<int EPI, bool BIAS, int NP, int DT>
__global__ __launch_bounds__(256, NP == 1 ? 4 : 2) void gemm3_nt(
    const bf16* __restrict__ Ah, const bf16* __restrict__ Al,
    const bf16* __restrict__ Bh, const bf16* __restrict__ Bl,
    const float* __restrict__ bias, void* __restrict__ Cg, void* __restrict__ Cl,
    const int K, const int ldab, const int ldc,
    const long sA, const long sB, const long sC)
{
    constexpr int TILE = 128 * 64;                 // elems per plane
    constexpr int LOSZ = (NP == 3) ? TILE : 8;     // lo planes only for NP=3
    __shared__ __align__(16) bf16 smAh[TILE];
    __shared__ __align__(16) bf16 smBh[TILE];
    __shared__ __align__(16) bf16 smAl[LOSZ];
    __shared__ __align__(16) bf16 smBl[LOSZ];

    const int tid  = threadIdx.x;
    const int lane = tid & 63;
    const int wave = tid >> 6;
    const int wr   = (wave >> 1) << 6;
    const int wc   = (wave & 1) << 6;
    const int l15  = lane & 15;
    const int q4   = lane >> 4;

    // ---- block swizzle: XCD chunk + 4x4 output supertile (bijective) ----
    int bx = blockIdx.x, by = blockIdx.y;
    {
        const int gx = gridDim.x, gy = gridDim.y;
        if (((gx & 3) | (gy & 3)) == 0) {
            const int tot = gx * gy;               // multiple of 16
            const int n   = bx + gx * by;
            const int l   = (n & 7) * (tot >> 3) + (n >> 3);   // XCD chunk
            const int st  = l >> 4, pos = l & 15;              // supertile
            bx = (st % (gx >> 2)) * 4 + (pos & 3);
            by = (st / (gx >> 2)) * 4 + (pos >> 2);
        }
    }

    const long aoff = (long)blockIdx.z * sA + (long)bx * 128 * ldab;
    const long boff = (long)blockIdx.z * sB + (long)by * 128 * ldab;
    const bf16* pAh = Ah + aoff;
    const bf16* pAl = (NP == 3) ? Al + aoff : nullptr;
    const bf16* pBh = Bh + boff;
    const bf16* pBl = (NP == 3) ? Bl + boff : nullptr;

    int srow[4], scol[4];
#pragma unroll
    for (int it = 0; it < 4; ++it) {
        int chunk = it * 256 + tid;
        int m = chunk >> 3;
        srow[it] = m;
        scol[it] = ((chunk & 7) ^ (m & 7)) * 8;
    }

    f32x4 acc[4][4] = {};

    for (int k0 = 0; k0 < K; k0 += 64) {
#pragma unroll
        for (int it = 0; it < 4; ++it) {
            const long go = (long)srow[it] * ldab + (k0 + scol[it]);
            const size_t lo = (size_t)(it * 256 + (wave << 6)) * 8;   // linear fill
            GLL(pAh + go, smAh + lo);
            if constexpr (NP == 3) GLL(pAl + go, smAl + lo);
            GLL(pBh + go, smBh + lo);
            if constexpr (NP == 3) GLL(pBl + go, smBl + lo);
        }
        __syncthreads();

#pragma unroll
        for (int kk = 0; kk < 2; ++kk) {
            bf16x8 avh[4], avl[4], bvh[4], bvl[4];
#pragma unroll
            for (int i = 0; i < 4; ++i) {
                const int rowa = wr + i * 16 + l15;
                const int ca = ((kk * 4 + q4) ^ (rowa & 7)) * 8;   // swizzled read
                avh[i] = *(const bf16x8*)(smAh + rowa * 64 + ca);
                if constexpr (NP == 3) avl[i] = *(const bf16x8*)(smAl + rowa * 64 + ca);
                const int rowb = wc + i * 16 + l15;
                const int cb = ((kk * 4 + q4) ^ (rowb & 7)) * 8;
                bvh[i] = *(const bf16x8*)(smBh + rowb * 64 + cb);
                if constexpr (NP == 3) bvl[i] = *(const bf16x8*)(smBl + rowb * 64 + cb);
            }
#pragma unroll
            for (int i = 0; i < 4; ++i)
#pragma unroll
                for (int j = 0; j < 4; ++j) {
                    if constexpr (DT == 1) {
                        acc[i][j] = __builtin_amdgcn_mfma_f32_16x16x32_f16(
                            *(const f16x8*)&avh[i], *(const f16x8*)&bvh[j],
                            acc[i][j], 0, 0, 0);
                    } else {
                        acc[i][j] = __builtin_amdgcn_mfma_f32_16x16x32_bf16(
                            avh[i], bvh[j], acc[i][j], 0, 0, 0);
                        if constexpr (NP == 3) {
                            acc[i][j] = __builtin_amdgcn_mfma_f32_16x16x32_bf16(
                                avl[i], bvh[j], acc[i][j], 0, 0, 0);
                            acc[i][j] = __builtin_amdgcn_mfma_f32_16x16x32_bf16(
                                avh[i], bvl[j], acc[i][j], 0, 0, 0);
                        }
                    }
                }
        }
        __syncthreads();
    }

    // epilogue: D col = lane&15, row = (lane>>4)*4 + e
    const long zC = (long)blockIdx.z * sC;
    const int gcol0 = by * 128 + wc + l15;
    const int grow0 = bx * 128 + wr + q4 * 4;
#pragma unroll
    for (int j = 0; j < 4; ++j) {
        const int col = gcol0 + j * 16;
        const float bvz = BIAS ? bias[col] : 0.0f;
#pragma unroll
        for (int i = 0; i < 4; ++i) {
            const int row = grow0 + i * 16;
            if (EPI == 7) {
                f16x4 o;
#pragma unroll
                for (int e = 0; e < 4; ++e) o[e] = (f16)(acc[i][j][e] + bvz);
                *(f16x4*)((f16*)Cg + zC + (long)col * ldc + row) = o;
            } else {
#pragma unroll
                for (int e = 0; e < 4; ++e) {
                    float v = acc[i][j][e] + bvz;
                    if (EPI == 1) v = geluf(v);
                    const long off = zC + (long)(row + e) * ldc + col;
                    if (EPI == 4) {
                        const bf16 hi = (bf16)v;
                        ((bf16*)Cg)[off] = hi;
                        ((bf16*)Cl)[off] = (bf16)(v - (float)hi);
                    } else if (EPI == 6) {
                        ((f16*)Cg)[off] = (f16)v;
                    } else {
                        ((float*)Cg)[off] = v;
                    }
                }
            }
        }
    }
}

// ---------------------------------------------------------------------------
// y = emb[x] + pos -> split bf16 + fp16 plane; vbias row-dot
// ---------------------------------------------------------------------------
__global__ __launch_bounds__(256) void embed_k(
    const int* __restrict__ x, const float* __restrict__ emb,
    bf16* __restrict__ yh, bf16* __restrict__ yl, f16* __restrict__ yf16,
    const float* __restrict__ wkbq, float* __restrict__ vb)
{
    const int bs = blockIdx.x;          // row
    const int s = bs & (SEQ - 1);
    const long e0 = (long)x[bs] * DM;
    const int d = threadIdx.x * 4;
    const float4 ev = *(const float4*)(emb + e0 + d);
    float o[4];
    const float fs = (float)s;
#pragma unroll
    for (int e = 0; e < 4; ++e) {
        const int dd = d + e;
        const float div = powf(10000.0f, (float)dd * (1.0f / 1024.0f));
        const float ang = fs / div;
        const float p = (dd & 1) ? cosf(ang) : sinf(ang);
        o[e] = ((const float*)&ev)[e] + p;
    }
    bf16x4 oh, ol; f16x4 of;
#pragma unroll
    for (int e = 0; e < 4; ++e) {
        oh[e] = (bf16)o[e];
        ol[e] = (bf16)(o[e] - (float)oh[e]);
        of[e] = (f16)o[e];
    }
    *(bf16x4*)(yh + (long)bs * DM + d) = oh;
    *(bf16x4*)(yl + (long)bs * DM + d) = ol;
    *(f16x4*) (yf16 + (long)bs * DM + d) = of;
    const float4 wv = *(const float4*)(wkbq + d);
    float sdot = o[0] * wv.x + o[1] * wv.y + o[2] * wv.z + o[3] * wv.w;
#pragma unroll
    for (int off = 32; off; off >>= 1) sdot += __shfl_xor(sdot, off);
    __shared__ float red[4];
    if ((threadIdx.x & 63) == 0) red[threadIdx.x >> 6] = sdot;
    __syncthreads();
    if (threadIdx.x == 0) vb[bs] = red[0] + red[1] + red[2] + red[3];
}

// ---------------------------------------------------------------------------
// f32 -> split bf16 straight copy
// ---------------------------------------------------------------------------
__global__ __launch_bounds__(256) void copy_split_k(
    const float* __restrict__ src, bf16* __restrict__ dh, bf16* __restrict__ dl)
{
    const long i = ((long)blockIdx.x * 256 + threadIdx.x) * 4;
    const float4 v = *(const float4*)(src + i);
    const float vv[4] = {v.x, v.y, v.z, v.w};
    bf16x4 oh, ol;
#pragma unroll
    for (int e = 0; e < 4; ++e) {
        const bf16 hi = (bf16)vv[e];
        oh[e] = hi;
        ol[e] = (bf16)(vv[e] - (float)hi);
    }
    *(bf16x4*)(dh + i) = oh;
    *(bf16x4*)(dl + i) = ol;
}

// ---------------------------------------------------------------------------
// 8-plane f32 reduce -> split bf16 + fp16 (straight, for MT)
// ---------------------------------------------------------------------------
__global__ __launch_bounds__(256) void reduce8s_k(
    const float* __restrict__ p, bf16* __restrict__ dh, bf16* __restrict__ dl,
    f16* __restrict__ df)
{
    const long i = ((long)blockIdx.x * 256 + threadIdx.x) * 4;
    const long PL = (long)1 << 20;
    float vv[4] = {0.f, 0.f, 0.f, 0.f};
#pragma unroll
    for (int q = 0; q < 8; ++q) {
        const float4 a = *(const float4*)(p + q * PL + i);
        vv[0] += a.x; vv[1] += a.y; vv[2] += a.z; vv[3] += a.w;
    }
    bf16x4 oh, ol; f16x4 of;
#pragma unroll
    for (int e = 0; e < 4; ++e) {
        const bf16 hi = (bf16)vv[e];
        oh[e] = hi;
        ol[e] = (bf16)(vv[e] - (float)hi);
        of[e] = (f16)vv[e];
    }
    *(bf16x4*)(dh + i) = oh;
    *(bf16x4*)(dl + i) = ol;
    *(f16x4*) (df + i) = of;
}

// ---------------------------------------------------------------------------
// 8-plane f32 reduce + TRANSPOSE -> split bf16 + fp16 (for W_vo^T, W_12^T)
// ---------------------------------------------------------------------------
__global__ __launch_bounds__(256) void reduce8t_k(
    const float* __restrict__ p, bf16* __restrict__ dsth, bf16* __restrict__ dstl,
    f16* __restrict__ dstf)
{
    __shared__ float tf[64][65];
    const long PL = (long)1 << 20;
    const int c0 = blockIdx.x * 64, r0 = blockIdx.y * 64;
    const int t = threadIdx.x;
    const int tr = t >> 4;
    const int tc = (t & 15) * 4;
#pragma unroll
    for (int pp = 0; pp < 4; ++pp) {
        const int r = tr + pp * 16;
        float vv[4] = {0.f, 0.f, 0.f, 0.f};
#pragma unroll
        for (int q = 0; q < 8; ++q) {
            const float4 v = *(const float4*)(p + q * PL + (long)(r0 + r) * 1024 + c0 + tc);
            vv[0] += v.x; vv[1] += v.y; vv[2] += v.z; vv[3] += v.w;
        }
#pragma unroll
        for (int e = 0; e < 4; ++e) tf[r][tc + e] = vv[e];
    }
    __syncthreads();
#pragma unroll
    for (int pp = 0; pp < 4; ++pp) {
        const int c = tr + pp * 16;
        bf16x4 oh, ol; f16x4 of;
#pragma unroll
        for (int e = 0; e < 4; ++e) {
            const float v = tf[tc + e][c];
            const bf16 hi = (bf16)v;
            oh[e] = hi;
            ol[e] = (bf16)(v - (float)hi);
            of[e] = (f16)v;
        }
        *(bf16x4*)(dsth + (long)(c0 + c) * 1024 + r0 + tc) = oh;
        *(bf16x4*)(dstl + (long)(c0 + c) * 1024 + r0 + tc) = ol;
        *(f16x4*) (dstf + (long)(c0 + c) * 1024 + r0 + tc) = of;
    }
}

// ---------------------------------------------------------------------------
// f32 -> split bf16 transpose (weights staged K-contiguous)
// ---------------------------------------------------------------------------
__global__ __launch_bounds__(256) void transpose_k(
    const float* __restrict__ src, bf16* __restrict__ dsth, bf16* __restrict__ dstl,
    int R, int C)
{
    __shared__ bf16 th[64][65];
    __shared__ bf16 tl[64][65];
    const int c0 = blockIdx.x * 64, r0 = blockIdx.y * 64;
    const int t = threadIdx.x;
    const int tr = t >> 4;
    const int tc = (t & 15) * 4;
#pragma unroll
    for (int p = 0; p < 4; ++p) {
        const int r = tr + p * 16;
        const float4 v = *(const float4*)(src + (long)(r0 + r) * C + c0 + tc);
        const float vv[4] = {v.x, v.y, v.z, v.w};
#pragma unroll
        for (int e = 0; e < 4; ++e) {
            const bf16 hi = (bf16)vv[e];
            th[r][tc + e] = hi;
            tl[r][tc + e] = (bf16)(vv[e] - (float)hi);
        }
    }
    __syncthreads();
#pragma unroll
    for (int p = 0; p < 4; ++p) {
        const int c = tr + p * 16;
        bf16x4 oh, ol;
#pragma unroll
        for (int e = 0; e < 4; ++e) { oh[e] = th[tc + e][c]; ol[e] = tl[tc + e][c]; }
        *(bf16x4*)(dsth + (long)(c0 + c) * R + r0 + tc) = oh;
        *(bf16x4*)(dstl + (long)(c0 + c) * R + r0 + tc) = ol;
    }
}

// ---------------------------------------------------------------------------
// wb[d] = sum_h W[d][h] * b[h]   (f32, W is [1024][4096])
// ---------------------------------------------------------------------------
__global__ __launch_bounds__(256) void matvec_wb_k(
    const float* __restrict__ W, const float* __restrict__ b, float* __restrict__ out)
{
    const int d = blockIdx.x;
    const int t = threadIdx.x;
    float s = 0.f;
    for (int h = t * 4; h < HD; h += 1024) {
        const float4 wv = *(const float4*)(W + (long)d * HD + h);
        const float4 bv = *(const float4*)(b + h);
        s += wv.x * bv.x + wv.y * bv.y + wv.z * bv.z + wv.w * bv.w;
    }
#pragma unroll
    for (int o = 32; o; o >>= 1) s += __shfl_xor(s, o);
    __shared__ float red[4];
    if ((t & 63) == 0) red[t >> 6] = s;
    __syncthreads();
    if (t == 0) out[d] = red[0] + red[1] + red[2] + red[3];
}

// ---------------------------------------------------------------------------
// out[j] = sum_h (BtH+BtL)[j][h] * b[h] + add[j]
// ---------------------------------------------------------------------------
__global__ __launch_bounds__(256) void matvec_bt_k(
    const bf16* __restrict__ bth, const bf16* __restrict__ btl,
    const float* __restrict__ b, const float* __restrict__ add,
    float* __restrict__ out)
{
    const int j = blockIdx.x;
    const int t = threadIdx.x;
    float s = 0.f;
    for (int h = t * 4; h < HD; h += 1024) {
        const bf16x4 hx = *(const bf16x4*)(bth + (long)j * HD + h);
        const bf16x4 lx = *(const bf16x4*)(btl + (long)j * HD + h);
        const float4 bv = *(const float4*)(b + h);
        s += ((float)hx[0] + (float)lx[0]) * bv.x + ((float)hx[1] + (float)lx[1]) * bv.y
           + ((float)hx[2] + (float)lx[2]) * bv.z + ((float)hx[3] + (float)lx[3]) * bv.w;
    }
#pragma unroll
    for (int o = 32; o; o >>= 1) s += __shfl_xor(s, o);
    __shared__ float red[4];
    if ((t & 63) == 0) red[t >> 6] = s;
    __syncthreads();
    if (t == 0) out[j] = red[0] + red[1] + red[2] + red[3] + add[j];
}

// ---------------------------------------------------------------------------
// Row softmax with key-side column bias -> fp16 P
// ---------------------------------------------------------------------------
__global__ __launch_bounds__(256) void softmax_k(
    const float* __restrict__ S, const float* __restrict__ v,
    f16* __restrict__ P)
{
    const long row = blockIdx.x;
    const float4* src = (const float4*)(S + (row << 11));
    const float* vr = v + (long)(row >> 11) * SEQ;
    const int t = threadIdx.x;
    float4 a = src[t], b = src[256 + t];
    const float4 va = *(const float4*)(vr + t * 4);
    const float4 vb = *(const float4*)(vr + 1024 + t * 4);
    a.x += va.x; a.y += va.y; a.z += va.z; a.w += va.w;
    b.x += vb.x; b.y += vb.y; b.z += vb.z; b.w += vb.w;
    float m = fmaxf(fmaxf(fmaxf(a.x, a.y), fmaxf(a.z, a.w)),
                    fmaxf(fmaxf(b.x, b.y), fmaxf(b.z, b.w)));
#pragma unroll
    for (int o = 32; o; o >>= 1) m = fmaxf(m, __shfl_xor(m, o));
    __shared__ float red1[4], red2[4];
    const int wv = t >> 6;
    if ((t & 63) == 0) red1[wv] = m;
    __syncthreads();
    m = fmaxf(fmaxf(red1[0], red1[1]), fmaxf(red1[2], red1[3]));

    a.x = expf(a.x - m); a.y = expf(a.y - m); a.z = expf(a.z - m); a.w = expf(a.w - m);
    b.x = expf(b.x - m); b.y = expf(b.y - m); b.z = expf(b.z - m); b.w = expf(b.w - m);
    float s = a.x + a.y + a.z + a.w + b.x + b.y + b.z + b.w;
#pragma unroll
    for (int o = 32; o; o >>= 1) s += __shfl_xor(s, o);
    if ((t & 63) == 0) red2[wv] = s;
    __syncthreads();
    s = red2[0] + red2[1] + red2[2] + red2[3];
    const float inv = 1.0f / s;

    f16x4 o0, o1;
    o0[0] = (f16)(a.x * inv); o0[1] = (f16)(a.y * inv);
    o0[2] = (f16)(a.z * inv); o0[3] = (f16)(a.w * inv);
    o1[0] = (f16)(b.x * inv); o1[1] = (f16)(b.y * inv);
    o1[2] = (f16)(b.z * inv); o1[3] = (f16)(b.w * inv);
    *(f16x4*)(P + (row << 11) + t * 4) = o0;
    *(f16x4*)(P + (row << 11) + 1024 + t * 4) = o1;
}

// ---------------------------------------------------------------------------
// LayerNorm over whole (S,D) sample; residual carried as split bf16 (hi+lo).
// ---------------------------------------------------------------------------
__global__ __launch_bounds__(256) void ln_stats_k(
    const bf16* __restrict__ yh, const bf16* __restrict__ yl,
    const float* __restrict__ r, float2* __restrict__ part)
{
    const int b = blockIdx.y;
    const long base = (long)b * SD + (long)blockIdx.x * (SD / 64);
    float s = 0.f, q = 0.f;
    for (int i = threadIdx.x; i < (SD / 64) / 4; i += 256) {
        const bf16x4 h = *(const bf16x4*)(yh + base + i * 4);
        const bf16x4 l = *(const bf16x4*)(yl + base + i * 4);
        const float4 c = *(const float4*)(r + base + i * 4);
        const float cc[4] = {c.x, c.y, c.z, c.w};
#pragma unroll
        for (int e = 0; e < 4; ++e) {
            const float xx = (float)h[e] + (float)l[e] + cc[e];
            s += xx; q += xx * xx;
        }
    }
#pragma unroll
    for (int o = 32; o; o >>= 1) { s += __shfl_xor(s, o); q += __shfl_xor(q, o); }
    __shared__ float rs[4], rq[4];
    const int wv = threadIdx.x >> 6;
    if ((threadIdx.x & 63) == 0) { rs[wv] = s; rq[wv] = q; }
    __syncthreads();
    if (threadIdx.x == 0)
        part[b * 64 + blockIdx.x] = make_float2(rs[0] + rs[1] + rs[2] + rs[3],
                                                rq[0] + rq[1] + rq[2] + rq[3]);
}

__global__ void ln_fin_k(const float2* __restrict__ part, float2* __restrict__ stats)
{
    const int b = blockIdx.x;
    const float2 p = part[b * 64 + threadIdx.x];
    float s = p.x, q = p.y;
#pragma unroll
    for (int o = 32; o; o >>= 1) { s += __shfl_xor(s, o); q += __shfl_xor(q, o); }
    if (threadIdx.x == 0) {
        const float inv_n = 1.0f / (float)SD;
        const float mean = s * inv_n;
        const float var = fmaxf(q * inv_n - mean * mean, 0.f);
        stats[b] = make_float2(mean, rsqrtf(var + 1e-5f));
    }
}

// ln_apply: one block per row. Writes split bf16 + fp16 (+f32 out) and
// optionally the NEXT layer's key-side bias dot (vb[row] = dot(o, wkbq)).
__global__ __launch_bounds__(256) void ln_apply_k(
    const bf16* __restrict__ yh_in, const bf16* __restrict__ yl_in,
    const float* __restrict__ r,
    const float* __restrict__ w, const float* __restrict__ bb,
    const float2* __restrict__ stats,
    bf16* __restrict__ yh_out, bf16* __restrict__ yl_out, f16* __restrict__ yf16,
    float* __restrict__ fout,
    const float* __restrict__ wkbq, float* __restrict__ vb)
{
    const long i = (long)blockIdx.x * 1024 + threadIdx.x * 4;
    const int smp = (int)(i >> 21);
    const long sd = i & (SD - 1);
    const float2 st = stats[smp];
    const bf16x4 h = *(const bf16x4*)(yh_in + i);
    const bf16x4 l = *(const bf16x4*)(yl_in + i);
    const float4 c = *(const float4*)(r + i);
    const float4 wv = *(const float4*)(w + sd);
    const float4 bv = *(const float4*)(bb + sd);
    const float cc[4] = {c.x, c.y, c.z, c.w};
    const float ww[4] = {wv.x, wv.y, wv.z, wv.w};
    const float bbx[4] = {bv.x, bv.y, bv.z, bv.w};
    float o[4];
#pragma unroll
    for (int e = 0; e < 4; ++e) {
        const float xx = (float)h[e] + (float)l[e] + cc[e];
        o[e] = (xx - st.x) * st.y * ww[e] + bbx[e];
    }
    bf16x4 oh, ol; f16x4 of;
#pragma unroll
    for (int e = 0; e < 4; ++e) {
        oh[e] = (bf16)o[e];
        ol[e] = (bf16)(o[e] - (float)oh[e]);
        of[e] = (f16)o[e];
    }
    *(bf16x4*)(yh_out + i) = oh;
    *(bf16x4*)(yl_out + i) = ol;
    *(f16x4*) (yf16 + i) = of;
    if (fout != nullptr) *(float4*)(fout + i) = *(float4*)o;
    if (vb != nullptr) {
        const int d = threadIdx.x * 4;
        const float4 kv = *(const float4*)(wkbq + d);
        float sdot = o[0] * kv.x + o[1] * kv.y + o[2] * kv.z + o[3] * kv.w;
#pragma unroll
        for (int off = 32; off; off >>= 1) sdot += __shfl_xor(sdot, off);
        __shared__ float red[4];
        if ((threadIdx.x & 63) == 0) red[threadIdx.x >> 6] = sdot;
        __syncthreads();
        if (threadIdx.x == 0) vb[blockIdx.x] = red[0] + red[1] + red[2] + red[3];
    }
}

// ---------------------------------------------------------------------------
extern "C" void kernel_launch(void* const* d_in, const int* in_sizes, int n_in,
                              void* d_out, int out_size, void* d_ws, size_t ws_size,
                              hipStream_t stream)
{
    (void)in_sizes; (void)n_in; (void)out_size; (void)ws_size;

    const int*   x    = (const int*)  d_in[0];
    const float* emb  = (const float*)d_in[1];
    const float* wq   = (const float*)d_in[2];
    const float* bq   = (const float*)d_in[3];
    const float* wk   = (const float*)d_in[4];
    const float* bk   = (const float*)d_in[5];
    const float* wv   = (const float*)d_in[6];
    const float* bv   = (const float*)d_in[7];
    const float* wo   = (const float*)d_in[8];
    const float* bo   = (const float*)d_in[9];
    const float* w1   = (const float*)d_in[10];
    const float* b1   = (const float*)d_in[11];
    const float* w2   = (const float*)d_in[12];
    const float* b2   = (const float*)d_in[13];
    const float* ln1w = (const float*)d_in[14];
    const float* ln1b = (const float*)d_in[15];
    const float* ln2w = (const float*)d_in[16];
    const float* ln2b = (const float*)d_in[17];
    (void)bk;   // cancels in softmax (row-constant)

    // Workspace — peak ~324 MiB (≤384 proven-safe).
    char* ws = (char*)d_ws;
    const size_t MB = (size_t)1 << 20;
    bf16*   ybh   = (bf16*) (ws);                  //  16 MiB residual hi
    bf16*   ybl   = (bf16*) (ws + 16  * MB);       //  16 MiB residual lo
    f16*    yf16  = (f16*)  (ws + 32  * MB);       //  16 MiB residual fp16
    bf16*   S0h   = (bf16*) (ws + 48  * MB);       //   8 MiB weight slot 0 hi
    bf16*   S0l   = (bf16*) (ws + 56  * MB);       //   8 MiB weight slot 0 lo
    bf16*   S1h   = (bf16*) (ws + 64  * MB);       //   8 MiB weight slot 1 hi
    bf16*   S1l   = (bf16*) (ws + 72  * MB);       //   8 MiB weight slot 1 lo
    bf16*   MTh   = (bf16*) (ws + 80  * MB);       //   2 MiB
    bf16*   MTl   = (bf16*) (ws + 82  * MB);       //   2 MiB
    f16*    MTf   = (f16*)  (ws + 84  * MB);       //   2 MiB
    bf16*   VOh   = (bf16*) (ws + 86  * MB);       //   2 MiB
    bf16*   VOl   = (bf16*) (ws + 88  * MB);       //   2 MiB
    f16*    VOf   = (f16*)  (ws + 90  * MB);       //   2 MiB
    bf16*   W12h  = (bf16*) (ws + 92  * MB);       //   2 MiB
    bf16*   W12l  = (bf16*) (ws + 94  * MB);       //   2 MiB
    f16*    W12f  = (f16*)  (ws + 96  * MB);       //   2 MiB
    float*  wkbq2 = (float*)(ws + 98  * MB);                // 2 x 4 KiB
    float*  c_vo  = (float*)(ws + 98  * MB + 0x10000);      // 4 KiB
    float*  c_12  = (float*)(ws + 98  * MB + 0x20000);      // 4 KiB
    float*  vbias = (float*)(ws + 98  * MB + 0x30000);      // 32 KiB
    float2* part  = (float2*)(ws + 98 * MB + 0x40000);
    float2* stats = (float2*)(ws + 98 * MB + 0x50000);
    float*  wtmp8 = (float*)(ws + 100 * MB);       //  32 MiB K-split f32 partials
    bf16*   zh    = (bf16*) (ws + 132 * MB);       //  16 MiB z hi [8192][1024]
    bf16*   zl    = (bf16*) (ws + 148 * MB);       //  16 MiB z lo
    f16*    zf    = (f16*)  (ws + 164 * MB);       //  16 MiB z fp16
    f16*    uTf   = (f16*)  (ws + 180 * MB);       //  16 MiB u^T fp16 [4][1024][2048]
    float*  scf   = (float*)(ws + 196 * MB);       //  64 MiB scores f32 [4][2048][2048]
    f16*    Pf    = (f16*)  (ws + 260 * MB);       //  32 MiB probs fp16
    float*  attout= (float*)(ws + 292 * MB);       //  32 MiB f32 [8192][1024]
    float*  ffnf  = attout;

    const long TSZ = (long)DM * HD;

    // both layers' key-side weight-bias vectors (weight-only, precompute)
    matvec_wb_k<<<1024, 256, 0, stream>>>(wk + 0 * TSZ, bq + 0 * HD, wkbq2);
    matvec_wb_k<<<1024, 256, 0, stream>>>(wk + 1 * TSZ, bq + 1 * HD, wkbq2 + 0x4000 / 4);

    embed_k<<<NB * SEQ, 256, 0, stream>>>(x, emb, ybh, ybl, yf16, wkbq2, vbias);

    for (int l = 0; l < 2; ++l) {
        const float* wkbq_next = wkbq2 + 0x4000 / 4;   // layer-1 vector

        // ============ score path ============
        copy_split_k<<<4096, 256, 0, stream>>>(wq + l * TSZ, S0h, S0l);
        copy_split_k<<<4096, 256, 0, stream>>>(wk + l * TSZ, S1h, S1l);
        // MT = Wk·Wq^T (K-split x8, NP=3, f32 partials)
        gemm3_nt<0, false, 3, 0><<<dim3(8, 8, 8), 256, 0, stream>>>(
            S1h, S1l, S0h, S0l, nullptr, wtmp8, nullptr,
            512, HD, 1024, 512, 512, (long)1 << 20);
        reduce8s_k<<<1024, 256, 0, stream>>>(wtmp8, MTh, MTl, MTf);
        if (l == 0) {
            // strict: z and scores NP=3 bf16-split (double-softmax amplified)
            gemm3_nt<4, false, 3, 0><<<dim3(64, 8, 1), 256, 0, stream>>>(
                ybh, ybl, MTh, MTl, nullptr, zh, zl, DM, DM, DM, 0, 0, 0);
            gemm3_nt<0, false, 3, 0><<<dim3(16, 16, NB), 256, 0, stream>>>(
                zh, zl, ybh, ybl, nullptr, scf, nullptr,
                DM, DM, SEQ, (long)SD, (long)SD, (long)SEQ * SEQ);
        } else {
            // relaxed: fp16 single-pass (feeds output only)
            gemm3_nt<6, false, 1, 1><<<dim3(64, 8, 1), 256, 0, stream>>>(
                (const bf16*)yf16, nullptr, (const bf16*)MTf, nullptr, nullptr,
                zf, nullptr, DM, DM, DM, 0, 0, 0);
            gemm3_nt<0, false, 1, 1><<<dim3(16, 16, NB), 256, 0, stream>>>(
                (const bf16*)zf, nullptr, (const bf16*)yf16, nullptr, nullptr,
                scf, nullptr, DM, DM, SEQ, (long)SD, (long)SD, (long)SEQ * SEQ);
        }
        softmax_k<<<NB * SEQ, 256, 0, stream>>>(scf, vbias, Pf);

        // ============ value path: W_vo = Wv·Wo ============
        copy_split_k<<<4096, 256, 0, stream>>>(wv + l * TSZ, S0h, S0l);
        transpose_k <<<dim3(16, 64), 256, 0, stream>>>(wo + l * TSZ, S1h, S1l, HD, DM);
        matvec_bt_k<<<1024, 256, 0, stream>>>(S1h, S1l, bv + l * HD, bo + l * DM, c_vo);
        if (l == 0)
            gemm3_nt<0, false, 3, 0><<<dim3(8, 8, 8), 256, 0, stream>>>(
                S0h, S0l, S1h, S1l, nullptr, wtmp8, nullptr,
                512, HD, 1024, 512, 512, (long)1 << 20);
        else
            gemm3_nt<0, false, 1, 0><<<dim3(8, 8, 8), 256, 0, stream>>>(
                S0h, nullptr, S1h, nullptr, nullptr, wtmp8, nullptr,
                512, HD, 1024, 512, 512, (long)1 << 20);
        reduce8t_k<<<dim3(16, 16), 256, 0, stream>>>(wtmp8, VOh, VOl, VOf);
        // u^T = (y·W_vo)^T -> fp16 [4][1024][2048]
        if (l == 0)   // accurate compute (NP=3), fp16 storage
            gemm3_nt<7, false, 3, 0><<<dim3(16, 8, NB), 256, 0, stream>>>(
                ybh, ybl, VOh, VOl, nullptr, uTf, nullptr,
                DM, DM, SEQ, (long)SD, 0, (long)DM * SEQ);
        else
            gemm3_nt<7, false, 1, 1><<<dim3(16, 8, NB), 256, 0, stream>>>(
                (const bf16*)yf16, nullptr, (const bf16*)VOf, nullptr, nullptr,
                uTf, nullptr, DM, DM, SEQ, (long)SD, 0, (long)DM * SEQ);
        // attout = P·u + c_vo (fp16 NP=1 both layers)
        gemm3_nt<0, true, 1, 1><<<dim3(16, 8, NB), 256, 0, stream>>>(
            (const bf16*)Pf, nullptr, (const bf16*)uTf, nullptr, c_vo, attout, nullptr,
            SEQ, SEQ, DM, (long)SEQ * SEQ, (long)DM * SEQ, (long)SEQ * DM);
        // LN1(y + attout)
        ln_stats_k<<<dim3(64, NB), 256, 0, stream>>>(ybh, ybl, attout, part);
        ln_fin_k  <<<NB, 64, 0, stream>>>(part, stats);
        ln_apply_k<<<8192, 256, 0, stream>>>(ybh, ybl, attout,
                                             ln1w + (long)l * SD, ln1b + (long)l * SD,
                                             stats, ybh, ybl, yf16, nullptr,
                                             nullptr, nullptr);

        // ============ FFN path: W_12 = W1·W2 (exact collapse) ============
        copy_split_k<<<4096, 256, 0, stream>>>(w1 + l * TSZ, S0h, S0l);
        transpose_k <<<dim3(16, 64), 256, 0, stream>>>(w2 + l * TSZ, S1h, S1l, HD, DM);
        matvec_bt_k<<<1024, 256, 0, stream>>>(S1h, S1l, b1 + l * HD, b2 + l * DM, c_12);
        if (l == 0)
            gemm3_nt<0, false, 3, 0><<<dim3(8, 8, 8), 256, 0, stream>>>(
                S0h, S0l, S1h, S1l, nullptr, wtmp8, nullptr,
                512, HD, 1024, 512, 512, (long)1 << 20);
        else
            gemm3_nt<0, false, 1, 0><<<dim3(8, 8, 8), 256, 0, stream>>>(
                S0h, nullptr, S1h, nullptr, nullptr, wtmp8, nullptr,
                512, HD, 1024, 512, 512, (long)1 << 20);
        reduce8t_k<<<dim3(16, 16), 256, 0, stream>>>(wtmp8, W12h, W12l, W12f);
        // ffn = gelu(y·W_12 + c_12) (fp16 NP=1)
        gemm3_nt<1, true, 1, 1><<<dim3(64, 8, 1), 256, 0, stream>>>(
            (const bf16*)yf16, nullptr, (const bf16*)W12f, nullptr, c_12,
            ffnf, nullptr, DM, DM, DM, 0, 0, 0);
        // LN2; layer-0 apply also emits next layer's vbias; layer-1 writes d_out
        float* fdst = (l == 1) ? (float*)d_out : nullptr;
        ln_stats_k<<<dim3(64, NB), 256, 0, stream>>>(ybh, ybl, ffnf, part);
        ln_fin_k  <<<NB, 64, 0, stream>>>(part, stats);
        ln_apply_k<<<8192, 256, 0, stream>>>(ybh, ybl, ffnf,
                                             ln2w + (long)l * SD, ln2b + (long)l * SD,
                                             stats, ybh, ybl, yf16, fdst,
                                             (l == 0) ? wkbq_next : nullptr,
                                             (l == 0) ? vbias : nullptr);
    }
}

// Round 17
// 986.684 us; speedup vs baseline: 1.1560x; 1.0321x over previous
//
#include <hip/hip_runtime.h>
#include <cstdint>
#include <cstddef>

using bf16 = __bf16;
using f16  = _Float16;
typedef float f32x4 __attribute__((ext_vector_type(4)));
typedef bf16 bf16x8 __attribute__((ext_vector_type(8)));
typedef bf16 bf16x4 __attribute__((ext_vector_type(4)));
typedef f16  f16x8  __attribute__((ext_vector_type(8)));
typedef f16  f16x4  __attribute__((ext_vector_type(4)));

#define NB 4           // batch
#define SEQ 2048
#define DM 1024        // d_model
#define HD 4096        // hidden
#define SD (SEQ*DM)    // 2^21 elems per sample

__device__ __forceinline__ float geluf(float v) {
    return 0.5f * v * (1.0f + erff(v * 0.70710678118654752f));
}

#define GLL(gp, lp) __builtin_amdgcn_global_load_lds( \
    (const __attribute__((address_space(1))) void*)(gp), \
    (__attribute__((address_space(3))) void*)(lp), 16, 0, 0)

// ---------------------------------------------------------------------------
// Precision-tiered NT GEMM (proven single-buffer structure + block swizzle):
//   NP=3 (DT=0): C = Ah*Bh + Al*Bh + Ah*Bl  (split bf16, ~17-bit mantissa)
//   NP=1, DT=0 : C = Ah*Bh                  (plain bf16)
//   NP=1, DT=1 : C = A*B with fp16 operands (10-bit mantissa, 1 pass)
// EPI: 0 = f32 (+bias), 1 = f32 gelu (+bias), 4 = split bf16 store,
//      6 = fp16 store, 7 = fp16 transposed store
// ---------------------------------------------------------------------------
template<int EPI, bool BIAS, int NP, int DT>
__global__ __launch_bounds__(256, NP == 1 ? 4 : 2) void gemm3_nt(
    const bf16* __restrict__ Ah, const bf16* __restrict__ Al,
    const bf16* __restrict__ Bh, const bf16* __restrict__ Bl,
    const float* __restrict__ bias, void* __restrict__ Cg, void* __restrict__ Cl,
    const int K, const int ldab, const int ldc,
    const long sA, const long sB, const long sC)
{
    constexpr int TILE = 128 * 64;                 // elems per plane
    constexpr int LOSZ = (NP == 3) ? TILE : 8;     // lo planes only for NP=3
    __shared__ __align__(16) bf16 smAh[TILE];
    __shared__ __align__(16) bf16 smBh[TILE];
    __shared__ __align__(16) bf16 smAl[LOSZ];
    __shared__ __align__(16) bf16 smBl[LOSZ];

    const int tid  = threadIdx.x;
    const int lane = tid & 63;
    const int wave = tid >> 6;
    const int wr   = (wave >> 1) << 6;
    const int wc   = (wave & 1) << 6;
    const int l15  = lane & 15;
    const int q4   = lane >> 4;

    // ---- block swizzle: XCD chunk + 4x4 output supertile (bijective) ----
    int bx = blockIdx.x, by = blockIdx.y;
    {
        const int gx = gridDim.x, gy = gridDim.y;
        if (((gx & 3) | (gy & 3)) == 0) {
            const int tot = gx * gy;               // multiple of 16
            const int n   = bx + gx * by;
            const int l   = (n & 7) * (tot >> 3) + (n >> 3);   // XCD chunk
            const int st  = l >> 4, pos = l & 15;              // supertile
            bx = (st % (gx >> 2)) * 4 + (pos & 3);
            by = (st / (gx >> 2)) * 4 + (pos >> 2);
        }
    }

    const long aoff = (long)blockIdx.z * sA + (long)bx * 128 * ldab;
    const long boff = (long)blockIdx.z * sB + (long)by * 128 * ldab;
    const bf16* pAh = Ah + aoff;
    const bf16* pAl = (NP == 3) ? Al + aoff : nullptr;
    const bf16* pBh = Bh + boff;
    const bf16* pBl = (NP == 3) ? Bl + boff : nullptr;

    int srow[4], scol[4];
#pragma unroll
    for (int it = 0; it < 4; ++it) {
        int chunk = it * 256 + tid;
        int m = chunk >> 3;
        srow[it] = m;
        scol[it] = ((chunk & 7) ^ (m & 7)) * 8;
    }

    f32x4 acc[4][4] = {};

    for (int k0 = 0; k0 < K; k0 += 64) {
#pragma unroll
        for (int it = 0; it < 4; ++it) {
            const long go = (long)srow[it] * ldab + (k0 + scol[it]);
            const size_t lo = (size_t)(it * 256 + (wave << 6)) * 8;   // linear fill
            GLL(pAh + go, smAh + lo);
            if constexpr (NP == 3) GLL(pAl + go, smAl + lo);
            GLL(pBh + go, smBh + lo);
            if constexpr (NP == 3) GLL(pBl + go, smBl + lo);
        }
        __syncthreads();

#pragma unroll
        for (int kk = 0; kk < 2; ++kk) {
            bf16x8 avh[4], avl[4], bvh[4], bvl[4];
#pragma unroll
            for (int i = 0; i < 4; ++i) {
                const int rowa = wr + i * 16 + l15;
                const int ca = ((kk * 4 + q4) ^ (rowa & 7)) * 8;   // swizzled read
                avh[i] = *(const bf16x8*)(smAh + rowa * 64 + ca);
                if constexpr (NP == 3) avl[i] = *(const bf16x8*)(smAl + rowa * 64 + ca);
                const int rowb = wc + i * 16 + l15;
                const int cb = ((kk * 4 + q4) ^ (rowb & 7)) * 8;
                bvh[i] = *(const bf16x8*)(smBh + rowb * 64 + cb);
                if constexpr (NP == 3) bvl[i] = *(const bf16x8*)(smBl + rowb * 64 + cb);
            }
#pragma unroll
            for (int i = 0; i < 4; ++i)
#pragma unroll
                for (int j = 0; j < 4; ++j) {
                    if constexpr (DT == 1) {
                        acc[i][j] = __builtin_amdgcn_mfma_f32_16x16x32_f16(
                            *(const f16x8*)&avh[i], *(const f16x8*)&bvh[j],
                            acc[i][j], 0, 0, 0);
                    } else {
                        acc[i][j] = __builtin_amdgcn_mfma_f32_16x16x32_bf16(
                            avh[i], bvh[j], acc[i][j], 0, 0, 0);
                        if constexpr (NP == 3) {
                            acc[i][j] = __builtin_amdgcn_mfma_f32_16x16x32_bf16(
                                avl[i], bvh[j], acc[i][j], 0, 0, 0);
                            acc[i][j] = __builtin_amdgcn_mfma_f32_16x16x32_bf16(
                                avh[i], bvl[j], acc[i][j], 0, 0, 0);
                        }
                    }
                }
        }
        __syncthreads();
    }

    // epilogue: D col = lane&15, row = (lane>>4)*4 + e
    const long zC = (long)blockIdx.z * sC;
    const int gcol0 = by * 128 + wc + l15;
    const int grow0 = bx * 128 + wr + q4 * 4;
#pragma unroll
    for (int j = 0; j < 4; ++j) {
        const int col = gcol0 + j * 16;
        const float bvz = BIAS ? bias[col] : 0.0f;
#pragma unroll
        for (int i = 0; i < 4; ++i) {
            const int row = grow0 + i * 16;
            if (EPI == 7) {
                f16x4 o;
#pragma unroll
                for (int e = 0; e < 4; ++e) o[e] = (f16)(acc[i][j][e] + bvz);
                *(f16x4*)((f16*)Cg + zC + (long)col * ldc + row) = o;
            } else {
#pragma unroll
                for (int e = 0; e < 4; ++e) {
                    float v = acc[i][j][e] + bvz;
                    if (EPI == 1) v = geluf(v);
                    const long off = zC + (long)(row + e) * ldc + col;
                    if (EPI == 4) {
                        const bf16 hi = (bf16)v;
                        ((bf16*)Cg)[off] = hi;
                        ((bf16*)Cl)[off] = (bf16)(v - (float)hi);
                    } else if (EPI == 6) {
                        ((f16*)Cg)[off] = (f16)v;
                    } else {
                        ((float*)Cg)[off] = v;
                    }
                }
            }
        }
    }
}

// ---------------------------------------------------------------------------
// y = emb[x] + pos -> split bf16 + fp16 plane; vbias row-dot
// ---------------------------------------------------------------------------
__global__ __launch_bounds__(256) void embed_k(
    const int* __restrict__ x, const float* __restrict__ emb,
    bf16* __restrict__ yh, bf16* __restrict__ yl, f16* __restrict__ yf16,
    const float* __restrict__ wkbq, float* __restrict__ vb)
{
    const int bs = blockIdx.x;          // row
    const int s = bs & (SEQ - 1);
    const long e0 = (long)x[bs] * DM;
    const int d = threadIdx.x * 4;
    const float4 ev = *(const float4*)(emb + e0 + d);
    float o[4];
    const float fs = (float)s;
#pragma unroll
    for (int e = 0; e < 4; ++e) {
        const int dd = d + e;
        const float div = powf(10000.0f, (float)dd * (1.0f / 1024.0f));
        const float ang = fs / div;
        const float p = (dd & 1) ? cosf(ang) : sinf(ang);
        o[e] = ((const float*)&ev)[e] + p;
    }
    bf16x4 oh, ol; f16x4 of;
#pragma unroll
    for (int e = 0; e < 4; ++e) {
        oh[e] = (bf16)o[e];
        ol[e] = (bf16)(o[e] - (float)oh[e]);
        of[e] = (f16)o[e];
    }
    *(bf16x4*)(yh + (long)bs * DM + d) = oh;
    *(bf16x4*)(yl + (long)bs * DM + d) = ol;
    *(f16x4*) (yf16 + (long)bs * DM + d) = of;
    const float4 wv = *(const float4*)(wkbq + d);
    float sdot = o[0] * wv.x + o[1] * wv.y + o[2] * wv.z + o[3] * wv.w;
#pragma unroll
    for (int off = 32; off; off >>= 1) sdot += __shfl_xor(sdot, off);
    __shared__ float red[4];
    if ((threadIdx.x & 63) == 0) red[threadIdx.x >> 6] = sdot;
    __syncthreads();
    if (threadIdx.x == 0) vb[bs] = red[0] + red[1] + red[2] + red[3];
}

// ---------------------------------------------------------------------------
// f32 -> split bf16 straight copy (layer-0 amplified-path weights)
// ---------------------------------------------------------------------------
__global__ __launch_bounds__(256) void copy_split_k(
    const float* __restrict__ src, bf16* __restrict__ dh, bf16* __restrict__ dl)
{
    const long i = ((long)blockIdx.x * 256 + threadIdx.x) * 4;
    const float4 v = *(const float4*)(src + i);
    const float vv[4] = {v.x, v.y, v.z, v.w};
    bf16x4 oh, ol;
#pragma unroll
    for (int e = 0; e < 4; ++e) {
        const bf16 hi = (bf16)vv[e];
        oh[e] = hi;
        ol[e] = (bf16)(vv[e] - (float)hi);
    }
    *(bf16x4*)(dh + i) = oh;
    *(bf16x4*)(dl + i) = ol;
}

// ---------------------------------------------------------------------------
// f32 -> f16 straight copy
// ---------------------------------------------------------------------------
__global__ __launch_bounds__(256) void copy_f16_k(
    const float* __restrict__ src, f16* __restrict__ dst)
{
    const long i = ((long)blockIdx.x * 256 + threadIdx.x) * 4;
    const float4 v = *(const float4*)(src + i);
    f16x4 o;
    o[0] = (f16)v.x; o[1] = (f16)v.y; o[2] = (f16)v.z; o[3] = (f16)v.w;
    *(f16x4*)(dst + i) = o;
}

// ---------------------------------------------------------------------------
// f32 R x C -> f16 C x R transpose
// ---------------------------------------------------------------------------
__global__ __launch_bounds__(256) void transpose_f16_k(
    const float* __restrict__ src, f16* __restrict__ dst, int R, int C)
{
    __shared__ f16 tf[64][65];
    const int c0 = blockIdx.x * 64, r0 = blockIdx.y * 64;
    const int t = threadIdx.x;
    const int tr = t >> 4;
    const int tc = (t & 15) * 4;
#pragma unroll
    for (int p = 0; p < 4; ++p) {
        const int r = tr + p * 16;
        const float4 v = *(const float4*)(src + (long)(r0 + r) * C + c0 + tc);
        tf[r][tc] = (f16)v.x; tf[r][tc + 1] = (f16)v.y;
        tf[r][tc + 2] = (f16)v.z; tf[r][tc + 3] = (f16)v.w;
    }
    __syncthreads();
#pragma unroll
    for (int p = 0; p < 4; ++p) {
        const int c = tr + p * 16;
        f16x4 o;
        o[0] = tf[tc][c]; o[1] = tf[tc + 1][c]; o[2] = tf[tc + 2][c]; o[3] = tf[tc + 3][c];
        *(f16x4*)(dst + (long)(c0 + c) * R + r0 + tc) = o;
    }
}

// ---------------------------------------------------------------------------
// f32 -> split bf16 transpose (layer-0 Wo staging)
// ---------------------------------------------------------------------------
__global__ __launch_bounds__(256) void transpose_k(
    const float* __restrict__ src, bf16* __restrict__ dsth, bf16* __restrict__ dstl,
    int R, int C)
{
    __shared__ bf16 th[64][65];
    __shared__ bf16 tl[64][65];
    const int c0 = blockIdx.x * 64, r0 = blockIdx.y * 64;
    const int t = threadIdx.x;
    const int tr = t >> 4;
    const int tc = (t & 15) * 4;
#pragma unroll
    for (int p = 0; p < 4; ++p) {
        const int r = tr + p * 16;
        const float4 v = *(const float4*)(src + (long)(r0 + r) * C + c0 + tc);
        const float vv[4] = {v.x, v.y, v.z, v.w};
#pragma unroll
        for (int e = 0; e < 4; ++e) {
            const bf16 hi = (bf16)vv[e];
            th[r][tc + e] = hi;
            tl[r][tc + e] = (bf16)(vv[e] - (float)hi);
        }
    }
    __syncthreads();
#pragma unroll
    for (int p = 0; p < 4; ++p) {
        const int c = tr + p * 16;
        bf16x4 oh, ol;
#pragma unroll
        for (int e = 0; e < 4; ++e) { oh[e] = th[tc + e][c]; ol[e] = tl[tc + e][c]; }
        *(bf16x4*)(dsth + (long)(c0 + c) * R + r0 + tc) = oh;
        *(bf16x4*)(dstl + (long)(c0 + c) * R + r0 + tc) = ol;
    }
}

// ---------------------------------------------------------------------------
// 8-plane f32 reduce -> split bf16 (straight, MT layer 0)
// ---------------------------------------------------------------------------
__global__ __launch_bounds__(256) void reduce8s_k(
    const float* __restrict__ p, bf16* __restrict__ dh, bf16* __restrict__ dl)
{
    const long i = ((long)blockIdx.x * 256 + threadIdx.x) * 4;
    const long PL = (long)1 << 20;
    float vv[4] = {0.f, 0.f, 0.f, 0.f};
#pragma unroll
    for (int q = 0; q < 8; ++q) {
        const float4 a = *(const float4*)(p + q * PL + i);
        vv[0] += a.x; vv[1] += a.y; vv[2] += a.z; vv[3] += a.w;
    }
    bf16x4 oh, ol;
#pragma unroll
    for (int e = 0; e < 4; ++e) {
        const bf16 hi = (bf16)vv[e];
        oh[e] = hi;
        ol[e] = (bf16)(vv[e] - (float)hi);
    }
    *(bf16x4*)(dh + i) = oh;
    *(bf16x4*)(dl + i) = ol;
}

// ---------------------------------------------------------------------------
// 8-plane f32 reduce -> f16 (straight, MT layer 1)
// ---------------------------------------------------------------------------
__global__ __launch_bounds__(256) void reduce8sf_k(
    const float* __restrict__ p, f16* __restrict__ df)
{
    const long i = ((long)blockIdx.x * 256 + threadIdx.x) * 4;
    const long PL = (long)1 << 20;
    float vv[4] = {0.f, 0.f, 0.f, 0.f};
#pragma unroll
    for (int q = 0; q < 8; ++q) {
        const float4 a = *(const float4*)(p + q * PL + i);
        vv[0] += a.x; vv[1] += a.y; vv[2] += a.z; vv[3] += a.w;
    }
    f16x4 of;
#pragma unroll
    for (int e = 0; e < 4; ++e) of[e] = (f16)vv[e];
    *(f16x4*)(df + i) = of;
}

// ---------------------------------------------------------------------------
// 8-plane f32 reduce + TRANSPOSE -> split bf16 (VO layer 0)
// ---------------------------------------------------------------------------
__global__ __launch_bounds__(256) void reduce8t_k(
    const float* __restrict__ p, bf16* __restrict__ dsth, bf16* __restrict__ dstl)
{
    __shared__ float tf[64][65];
    const long PL = (long)1 << 20;
    const int c0 = blockIdx.x * 64, r0 = blockIdx.y * 64;
    const int t = threadIdx.x;
    const int tr = t >> 4;
    const int tc = (t & 15) * 4;
#pragma unroll
    for (int pp = 0; pp < 4; ++pp) {
        const int r = tr + pp * 16;
        float vv[4] = {0.f, 0.f, 0.f, 0.f};
#pragma unroll
        for (int q = 0; q < 8; ++q) {
            const float4 v = *(const float4*)(p + q * PL + (long)(r0 + r) * 1024 + c0 + tc);
            vv[0] += v.x; vv[1] += v.y; vv[2] += v.z; vv[3] += v.w;
        }
#pragma unroll
        for (int e = 0; e < 4; ++e) tf[r][tc + e] = vv[e];
    }
    __syncthreads();
#pragma unroll
    for (int pp = 0; pp < 4; ++pp) {
        const int c = tr + pp * 16;
        bf16x4 oh, ol;
#pragma unroll
        for (int e = 0; e < 4; ++e) {
            const float v = tf[tc + e][c];
            const bf16 hi = (bf16)v;
            oh[e] = hi;
            ol[e] = (bf16)(v - (float)hi);
        }
        *(bf16x4*)(dsth + (long)(c0 + c) * 1024 + r0 + tc) = oh;
        *(bf16x4*)(dstl + (long)(c0 + c) * 1024 + r0 + tc) = ol;
    }
}

// ---------------------------------------------------------------------------
// 8-plane f32 reduce + TRANSPOSE -> f16 (VO layer 1, W12 both layers)
// ---------------------------------------------------------------------------
__global__ __launch_bounds__(256) void reduce8tf_k(
    const float* __restrict__ p, f16* __restrict__ dstf)
{
    __shared__ float tf[64][65];
    const long PL = (long)1 << 20;
    const int c0 = blockIdx.x * 64, r0 = blockIdx.y * 64;
    const int t = threadIdx.x;
    const int tr = t >> 4;
    const int tc = (t & 15) * 4;
#pragma unroll
    for (int pp = 0; pp < 4; ++pp) {
        const int r = tr + pp * 16;
        float vv[4] = {0.f, 0.f, 0.f, 0.f};
#pragma unroll
        for (int q = 0; q < 8; ++q) {
            const float4 v = *(const float4*)(p + q * PL + (long)(r0 + r) * 1024 + c0 + tc);
            vv[0] += v.x; vv[1] += v.y; vv[2] += v.z; vv[3] += v.w;
        }
#pragma unroll
        for (int e = 0; e < 4; ++e) tf[r][tc + e] = vv[e];
    }
    __syncthreads();
#pragma unroll
    for (int pp = 0; pp < 4; ++pp) {
        const int c = tr + pp * 16;
        f16x4 of;
#pragma unroll
        for (int e = 0; e < 4; ++e) of[e] = (f16)tf[tc + e][c];
        *(f16x4*)(dstf + (long)(c0 + c) * 1024 + r0 + tc) = of;
    }
}

// ---------------------------------------------------------------------------
// wb[d] = sum_h W[d][h] * b[h]   (f32, W is [1024][4096])
// ---------------------------------------------------------------------------
__global__ __launch_bounds__(256) void matvec_wb_k(
    const float* __restrict__ W, const float* __restrict__ b, float* __restrict__ out)
{
    const int d = blockIdx.x;
    const int t = threadIdx.x;
    float s = 0.f;
    for (int h = t * 4; h < HD; h += 1024) {
        const float4 wv = *(const float4*)(W + (long)d * HD + h);
        const float4 bv = *(const float4*)(b + h);
        s += wv.x * bv.x + wv.y * bv.y + wv.z * bv.z + wv.w * bv.w;
    }
#pragma unroll
    for (int o = 32; o; o >>= 1) s += __shfl_xor(s, o);
    __shared__ float red[4];
    if ((t & 63) == 0) red[t >> 6] = s;
    __syncthreads();
    if (t == 0) out[d] = red[0] + red[1] + red[2] + red[3];
}

// ---------------------------------------------------------------------------
// out[j] = sum_h (BtH+BtL)[j][h] * b[h] + add[j]   (split bf16 Bt)
// ---------------------------------------------------------------------------
__global__ __launch_bounds__(256) void matvec_bt_k(
    const bf16* __restrict__ bth, const bf16* __restrict__ btl,
    const float* __restrict__ b, const float* __restrict__ add,
    float* __restrict__ out)
{
    const int j = blockIdx.x;
    const int t = threadIdx.x;
    float s = 0.f;
    for (int h = t * 4; h < HD; h += 1024) {
        const bf16x4 hx = *(const bf16x4*)(bth + (long)j * HD + h);
        const bf16x4 lx = *(const bf16x4*)(btl + (long)j * HD + h);
        const float4 bv = *(const float4*)(b + h);
        s += ((float)hx[0] + (float)lx[0]) * bv.x + ((float)hx[1] + (float)lx[1]) * bv.y
           + ((float)hx[2] + (float)lx[2]) * bv.z + ((float)hx[3] + (float)lx[3]) * bv.w;
    }
#pragma unroll
    for (int o = 32; o; o >>= 1) s += __shfl_xor(s, o);
    __shared__ float red[4];
    if ((t & 63) == 0) red[t >> 6] = s;
    __syncthreads();
    if (t == 0) out[j] = red[0] + red[1] + red[2] + red[3] + add[j];
}

// ---------------------------------------------------------------------------
// out[j] = sum_h Btf[j][h] * b[h] + add[j]   (f16 Bt)
// ---------------------------------------------------------------------------
__global__ __launch_bounds__(256) void matvec_btf_k(
    const f16* __restrict__ btf, const float* __restrict__ b,
    const float* __restrict__ add, float* __restrict__ out)
{
    const int j = blockIdx.x;
    const int t = threadIdx.x;
    float s = 0.f;
    for (int h = t * 4; h < HD; h += 1024) {
        const f16x4 hx = *(const f16x4*)(btf + (long)j * HD + h);
        const float4 bv = *(const float4*)(b + h);
        s += (float)hx[0] * bv.x + (float)hx[1] * bv.y
           + (float)hx[2] * bv.z + (float)hx[3] * bv.w;
    }
#pragma unroll
    for (int o = 32; o; o >>= 1) s += __shfl_xor(s, o);
    __shared__ float red[4];
    if ((t & 63) == 0) red[t >> 6] = s;
    __syncthreads();
    if (t == 0) out[j] = red[0] + red[1] + red[2] + red[3] + add[j];
}

// ---------------------------------------------------------------------------
// Row softmax with key-side column bias -> fp16 P
// ---------------------------------------------------------------------------
__global__ __launch_bounds__(256) void softmax_k(
    const float* __restrict__ S, const float* __restrict__ v,
    f16* __restrict__ P)
{
    const long row = blockIdx.x;
    const float4* src = (const float4*)(S + (row << 11));
    const float* vr = v + (long)(row >> 11) * SEQ;
    const int t = threadIdx.x;
    float4 a = src[t], b = src[256 + t];
    const float4 va = *(const float4*)(vr + t * 4);
    const float4 vb = *(const float4*)(vr + 1024 + t * 4);
    a.x += va.x; a.y += va.y; a.z += va.z; a.w += va.w;
    b.x += vb.x; b.y += vb.y; b.z += vb.z; b.w += vb.w;
    float m = fmaxf(fmaxf(fmaxf(a.x, a.y), fmaxf(a.z, a.w)),
                    fmaxf(fmaxf(b.x, b.y), fmaxf(b.z, b.w)));
#pragma unroll
    for (int o = 32; o; o >>= 1) m = fmaxf(m, __shfl_xor(m, o));
    __shared__ float red1[4], red2[4];
    const int wv = t >> 6;
    if ((t & 63) == 0) red1[wv] = m;
    __syncthreads();
    m = fmaxf(fmaxf(red1[0], red1[1]), fmaxf(red1[2], red1[3]));

    a.x = expf(a.x - m); a.y = expf(a.y - m); a.z = expf(a.z - m); a.w = expf(a.w - m);
    b.x = expf(b.x - m); b.y = expf(b.y - m); b.z = expf(b.z - m); b.w = expf(b.w - m);
    float s = a.x + a.y + a.z + a.w + b.x + b.y + b.z + b.w;
#pragma unroll
    for (int o = 32; o; o >>= 1) s += __shfl_xor(s, o);
    if ((t & 63) == 0) red2[wv] = s;
    __syncthreads();
    s = red2[0] + red2[1] + red2[2] + red2[3];
    const float inv = 1.0f / s;

    f16x4 o0, o1;
    o0[0] = (f16)(a.x * inv); o0[1] = (f16)(a.y * inv);
    o0[2] = (f16)(a.z * inv); o0[3] = (f16)(a.w * inv);
    o1[0] = (f16)(b.x * inv); o1[1] = (f16)(b.y * inv);
    o1[2] = (f16)(b.z * inv); o1[3] = (f16)(b.w * inv);
    *(f16x4*)(P + (row << 11) + t * 4) = o0;
    *(f16x4*)(P + (row << 11) + 1024 + t * 4) = o1;
}

// ---------------------------------------------------------------------------
// LayerNorm over whole (S,D) sample; residual carried as split bf16 (hi+lo).
// ---------------------------------------------------------------------------
__global__ __launch_bounds__(256) void ln_stats_k(
    const bf16* __restrict__ yh, const bf16* __restrict__ yl,
    const float* __restrict__ r, float2* __restrict__ part)
{
    const int b = blockIdx.y;
    const long base = (long)b * SD + (long)blockIdx.x * (SD / 64);
    float s = 0.f, q = 0.f;
    for (int i = threadIdx.x; i < (SD / 64) / 4; i += 256) {
        const bf16x4 h = *(const bf16x4*)(yh + base + i * 4);
        const bf16x4 l = *(const bf16x4*)(yl + base + i * 4);
        const float4 c = *(const float4*)(r + base + i * 4);
        const float cc[4] = {c.x, c.y, c.z, c.w};
#pragma unroll
        for (int e = 0; e < 4; ++e) {
            const float xx = (float)h[e] + (float)l[e] + cc[e];
            s += xx; q += xx * xx;
        }
    }
#pragma unroll
    for (int o = 32; o; o >>= 1) { s += __shfl_xor(s, o); q += __shfl_xor(q, o); }
    __shared__ float rs[4], rq[4];
    const int wv = threadIdx.x >> 6;
    if ((threadIdx.x & 63) == 0) { rs[wv] = s; rq[wv] = q; }
    __syncthreads();
    if (threadIdx.x == 0)
        part[b * 64 + blockIdx.x] = make_float2(rs[0] + rs[1] + rs[2] + rs[3],
                                                rq[0] + rq[1] + rq[2] + rq[3]);
}

__global__ void ln_fin_k(const float2* __restrict__ part, float2* __restrict__ stats)
{
    const int b = blockIdx.x;
    const float2 p = part[b * 64 + threadIdx.x];
    float s = p.x, q = p.y;
#pragma unroll
    for (int o = 32; o; o >>= 1) { s += __shfl_xor(s, o); q += __shfl_xor(q, o); }
    if (threadIdx.x == 0) {
        const float inv_n = 1.0f / (float)SD;
        const float mean = s * inv_n;
        const float var = fmaxf(q * inv_n - mean * mean, 0.f);
        stats[b] = make_float2(mean, rsqrtf(var + 1e-5f));
    }
}

// ln_apply: one block per row. Writes split bf16 + fp16 (+f32 out) and
// optionally the NEXT layer's key-side bias dot (vb[row] = dot(o, wkbq)).
__global__ __launch_bounds__(256) void ln_apply_k(
    const bf16* __restrict__ yh_in, const bf16* __restrict__ yl_in,
    const float* __restrict__ r,
    const float* __restrict__ w, const float* __restrict__ bb,
    const float2* __restrict__ stats,
    bf16* __restrict__ yh_out, bf16* __restrict__ yl_out, f16* __restrict__ yf16,
    float* __restrict__ fout,
    const float* __restrict__ wkbq, float* __restrict__ vb)
{
    const long i = (long)blockIdx.x * 1024 + threadIdx.x * 4;
    const int smp = (int)(i >> 21);
    const long sd = i & (SD - 1);
    const float2 st = stats[smp];
    const bf16x4 h = *(const bf16x4*)(yh_in + i);
    const bf16x4 l = *(const bf16x4*)(yl_in + i);
    const float4 c = *(const float4*)(r + i);
    const float4 wv = *(const float4*)(w + sd);
    const float4 bv = *(const float4*)(bb + sd);
    const float cc[4] = {c.x, c.y, c.z, c.w};
    const float ww[4] = {wv.x, wv.y, wv.z, wv.w};
    const float bbx[4] = {bv.x, bv.y, bv.z, bv.w};
    float o[4];
#pragma unroll
    for (int e = 0; e < 4; ++e) {
        const float xx = (float)h[e] + (float)l[e] + cc[e];
        o[e] = (xx - st.x) * st.y * ww[e] + bbx[e];
    }
    bf16x4 oh, ol; f16x4 of;
#pragma unroll
    for (int e = 0; e < 4; ++e) {
        oh[e] = (bf16)o[e];
        ol[e] = (bf16)(o[e] - (float)oh[e]);
        of[e] = (f16)o[e];
    }
    *(bf16x4*)(yh_out + i) = oh;
    *(bf16x4*)(yl_out + i) = ol;
    *(f16x4*) (yf16 + i) = of;
    if (fout != nullptr) *(float4*)(fout + i) = *(float4*)o;
    if (vb != nullptr) {
        const int d = threadIdx.x * 4;
        const float4 kv = *(const float4*)(wkbq + d);
        float sdot = o[0] * kv.x + o[1] * kv.y + o[2] * kv.z + o[3] * kv.w;
#pragma unroll
        for (int off = 32; off; off >>= 1) sdot += __shfl_xor(sdot, off);
        __shared__ float red[4];
        if ((threadIdx.x & 63) == 0) red[threadIdx.x >> 6] = sdot;
        __syncthreads();
        if (threadIdx.x == 0) vb[blockIdx.x] = red[0] + red[1] + red[2] + red[3];
    }
}

// ---------------------------------------------------------------------------
extern "C" void kernel_launch(void* const* d_in, const int* in_sizes, int n_in,
                              void* d_out, int out_size, void* d_ws, size_t ws_size,
                              hipStream_t stream)
{
    (void)in_sizes; (void)n_in; (void)out_size; (void)ws_size;

    const int*   x    = (const int*)  d_in[0];
    const float* emb  = (const float*)d_in[1];
    const float* wq   = (const float*)d_in[2];
    const float* bq   = (const float*)d_in[3];
    const float* wk   = (const float*)d_in[4];
    const float* bk   = (const float*)d_in[5];
    const float* wv   = (const float*)d_in[6];
    const float* bv   = (const float*)d_in[7];
    const float* wo   = (const float*)d_in[8];
    const float* bo   = (const float*)d_in[9];
    const float* w1   = (const float*)d_in[10];
    const float* b1   = (const float*)d_in[11];
    const float* w2   = (const float*)d_in[12];
    const float* b2   = (const float*)d_in[13];
    const float* ln1w = (const float*)d_in[14];
    const float* ln1b = (const float*)d_in[15];
    const float* ln2w = (const float*)d_in[16];
    const float* ln2b = (const float*)d_in[17];
    (void)bk;   // cancels in softmax (row-constant)

    // Workspace — peak ~324 MiB (≤384 proven-safe).
    char* ws = (char*)d_ws;
    const size_t MB = (size_t)1 << 20;
    bf16*   ybh   = (bf16*) (ws);                  //  16 MiB residual hi
    bf16*   ybl   = (bf16*) (ws + 16  * MB);       //  16 MiB residual lo
    f16*    yf16  = (f16*)  (ws + 32  * MB);       //  16 MiB residual fp16
    bf16*   S0h   = (bf16*) (ws + 48  * MB);       //   8 MiB slot A (split hi / f16)
    bf16*   S0l   = (bf16*) (ws + 56  * MB);       //   8 MiB slot B (split lo / f16)
    bf16*   S1h   = (bf16*) (ws + 64  * MB);       //   8 MiB slot C
    bf16*   S1l   = (bf16*) (ws + 72  * MB);       //   8 MiB slot D
    f16*    F0    = (f16*)  (ws + 48  * MB);       //   f16 view of slot A
    f16*    F1    = (f16*)  (ws + 56  * MB);       //   f16 view of slot B
    bf16*   MTh   = (bf16*) (ws + 80  * MB);       //   2 MiB
    bf16*   MTl   = (bf16*) (ws + 82  * MB);       //   2 MiB
    f16*    MTf   = (f16*)  (ws + 84  * MB);       //   2 MiB
    bf16*   VOh   = (bf16*) (ws + 86  * MB);       //   2 MiB
    bf16*   VOl   = (bf16*) (ws + 88  * MB);       //   2 MiB
    f16*    VOf   = (f16*)  (ws + 90  * MB);       //   2 MiB
    f16*    W12f  = (f16*)  (ws + 92  * MB);       //   2 MiB
    float*  wkbq2 = (float*)(ws + 98  * MB);                // 2 x 4 KiB
    float*  c_vo  = (float*)(ws + 98  * MB + 0x10000);      // 4 KiB
    float*  c_12  = (float*)(ws + 98  * MB + 0x20000);      // 4 KiB
    float*  vbias = (float*)(ws + 98  * MB + 0x30000);      // 32 KiB
    float2* part  = (float2*)(ws + 98 * MB + 0x40000);
    float2* stats = (float2*)(ws + 98 * MB + 0x50000);
    float*  wtmp8 = (float*)(ws + 100 * MB);       //  32 MiB K-split f32 partials
    bf16*   zh    = (bf16*) (ws + 132 * MB);       //  16 MiB z hi [8192][1024]
    bf16*   zl    = (bf16*) (ws + 148 * MB);       //  16 MiB z lo
    f16*    zf    = (f16*)  (ws + 164 * MB);       //  16 MiB z fp16
    f16*    uTf   = (f16*)  (ws + 180 * MB);       //  16 MiB u^T fp16 [4][1024][2048]
    float*  scf   = (float*)(ws + 196 * MB);       //  64 MiB scores f32 [4][2048][2048]
    f16*    Pf    = (f16*)  (ws + 260 * MB);       //  32 MiB probs fp16
    float*  attout= (float*)(ws + 292 * MB);       //  32 MiB f32 [8192][1024]
    float*  ffnf  = attout;

    const long TSZ = (long)DM * HD;

    // both layers' key-side weight-bias vectors (weight-only, precompute)
    matvec_wb_k<<<1024, 256, 0, stream>>>(wk + 0 * TSZ, bq + 0 * HD, wkbq2);
    matvec_wb_k<<<1024, 256, 0, stream>>>(wk + 1 * TSZ, bq + 1 * HD, wkbq2 + 0x4000 / 4);

    embed_k<<<NB * SEQ, 256, 0, stream>>>(x, emb, ybh, ybl, yf16, wkbq2, vbias);

    for (int l = 0; l < 2; ++l) {
        const float* wkbq_next = wkbq2 + 0x4000 / 4;   // layer-1 vector

        // ============ score path ============
        if (l == 0) {
            // strict NP=3 split (doubly softmax-amplified)
            copy_split_k<<<4096, 256, 0, stream>>>(wq + l * TSZ, S0h, S0l);
            copy_split_k<<<4096, 256, 0, stream>>>(wk + l * TSZ, S1h, S1l);
            gemm3_nt<0, false, 3, 0><<<dim3(8, 8, 8), 256, 0, stream>>>(
                S1h, S1l, S0h, S0l, nullptr, wtmp8, nullptr,
                512, HD, 1024, 512, 512, (long)1 << 20);
            reduce8s_k<<<1024, 256, 0, stream>>>(wtmp8, MTh, MTl);
            gemm3_nt<4, false, 3, 0><<<dim3(64, 8, 1), 256, 0, stream>>>(
                ybh, ybl, MTh, MTl, nullptr, zh, zl, DM, DM, DM, 0, 0, 0);
            gemm3_nt<0, false, 3, 0><<<dim3(16, 16, NB), 256, 0, stream>>>(
                zh, zl, ybh, ybl, nullptr, scf, nullptr,
                DM, DM, SEQ, (long)SD, (long)SD, (long)SEQ * SEQ);
        } else {
            // relaxed fp16 (feeds output only): fp16 K-split product, fp16 GEMMs
            copy_f16_k<<<4096, 256, 0, stream>>>(wq + l * TSZ, F0);
            copy_f16_k<<<4096, 256, 0, stream>>>(wk + l * TSZ, F1);
            gemm3_nt<0, false, 1, 1><<<dim3(8, 8, 8), 256, 0, stream>>>(
                (const bf16*)F1, nullptr, (const bf16*)F0, nullptr, nullptr,
                wtmp8, nullptr, 512, HD, 1024, 512, 512, (long)1 << 20);
            reduce8sf_k<<<1024, 256, 0, stream>>>(wtmp8, MTf);
            gemm3_nt<6, false, 1, 1><<<dim3(64, 8, 1), 256, 0, stream>>>(
                (const bf16*)yf16, nullptr, (const bf16*)MTf, nullptr, nullptr,
                zf, nullptr, DM, DM, DM, 0, 0, 0);
            gemm3_nt<0, false, 1, 1><<<dim3(16, 16, NB), 256, 0, stream>>>(
                (const bf16*)zf, nullptr, (const bf16*)yf16, nullptr, nullptr,
                scf, nullptr, DM, DM, SEQ, (long)SD, (long)SD, (long)SEQ * SEQ);
        }
        softmax_k<<<NB * SEQ, 256, 0, stream>>>(scf, vbias, Pf);

        // ============ value path: W_vo = Wv·Wo ============
        if (l == 0) {
            // NP=3 (feeds uT-l0 which feeds layer-2 amplified path via LN1)
            copy_split_k<<<4096, 256, 0, stream>>>(wv + l * TSZ, S0h, S0l);
            transpose_k <<<dim3(16, 64), 256, 0, stream>>>(wo + l * TSZ, S1h, S1l, HD, DM);
            matvec_bt_k<<<1024, 256, 0, stream>>>(S1h, S1l, bv + l * HD, bo + l * DM, c_vo);
            gemm3_nt<0, false, 3, 0><<<dim3(8, 8, 8), 256, 0, stream>>>(
                S0h, S0l, S1h, S1l, nullptr, wtmp8, nullptr,
                512, HD, 1024, 512, 512, (long)1 << 20);
            reduce8t_k<<<dim3(16, 16), 256, 0, stream>>>(wtmp8, VOh, VOl);
            gemm3_nt<7, false, 3, 0><<<dim3(16, 8, NB), 256, 0, stream>>>(
                ybh, ybl, VOh, VOl, nullptr, uTf, nullptr,
                DM, DM, SEQ, (long)SD, 0, (long)DM * SEQ);
        } else {
            // fp16 (consumer uT-l1 is fp16 anyway)
            copy_f16_k     <<<4096, 256, 0, stream>>>(wv + l * TSZ, F0);
            transpose_f16_k<<<dim3(16, 64), 256, 0, stream>>>(wo + l * TSZ, F1, HD, DM);
            matvec_btf_k<<<1024, 256, 0, stream>>>(F1, bv + l * HD, bo + l * DM, c_vo);
            gemm3_nt<0, false, 1, 1><<<dim3(8, 8, 8), 256, 0, stream>>>(
                (const bf16*)F0, nullptr, (const bf16*)F1, nullptr, nullptr,
                wtmp8, nullptr, 512, HD, 1024, 512, 512, (long)1 << 20);
            reduce8tf_k<<<dim3(16, 16), 256, 0, stream>>>(wtmp8, VOf);
            gemm3_nt<7, false, 1, 1><<<dim3(16, 8, NB), 256, 0, stream>>>(
                (const bf16*)yf16, nullptr, (const bf16*)VOf, nullptr, nullptr,
                uTf, nullptr, DM, DM, SEQ, (long)SD, 0, (long)DM * SEQ);
        }
        // attout = P·u + c_vo (fp16 NP=1 both layers)
        gemm3_nt<0, true, 1, 1><<<dim3(16, 8, NB), 256, 0, stream>>>(
            (const bf16*)Pf, nullptr, (const bf16*)uTf, nullptr, c_vo, attout, nullptr,
            SEQ, SEQ, DM, (long)SEQ * SEQ, (long)DM * SEQ, (long)SEQ * DM);
        // LN1(y + attout)
        ln_stats_k<<<dim3(64, NB), 256, 0, stream>>>(ybh, ybl, attout, part);
        ln_fin_k  <<<NB, 64, 0, stream>>>(part, stats);
        ln_apply_k<<<8192, 256, 0, stream>>>(ybh, ybl, attout,
                                             ln1w + (long)l * SD, ln1b + (long)l * SD,
                                             stats, ybh, ybl, yf16, nullptr,
                                             nullptr, nullptr);

        // ============ FFN path: W_12 = W1·W2 (exact collapse; consumer is
        // fp16 ffn GEMM in both layers -> fp16 product, K-split geometry) ====
        copy_f16_k     <<<4096, 256, 0, stream>>>(w1 + l * TSZ, F0);
        transpose_f16_k<<<dim3(16, 64), 256, 0, stream>>>(w2 + l * TSZ, F1, HD, DM);
        matvec_btf_k<<<1024, 256, 0, stream>>>(F1, b1 + l * HD, b2 + l * DM, c_12);
        gemm3_nt<0, false, 1, 1><<<dim3(8, 8, 8), 256, 0, stream>>>(
            (const bf16*)F0, nullptr, (const bf16*)F1, nullptr, nullptr,
            wtmp8, nullptr, 512, HD, 1024, 512, 512, (long)1 << 20);
        reduce8tf_k<<<dim3(16, 16), 256, 0, stream>>>(wtmp8, W12f);
        // ffn = gelu(y·W_12 + c_12) (fp16 NP=1)
        gemm3_nt<1, true, 1, 1><<<dim3(64, 8, 1), 256, 0, stream>>>(
            (const bf16*)yf16, nullptr, (const bf16*)W12f, nullptr, c_12,
            ffnf, nullptr, DM, DM, DM, 0, 0, 0);
        // LN2; layer-0 apply also emits next layer's vbias; layer-1 writes d_out
        float* fdst = (l == 1) ? (float*)d_out : nullptr;
        ln_stats_k<<<dim3(64, NB), 256, 0, stream>>>(ybh, ybl, ffnf, part);
        ln_fin_k  <<<NB, 64, 0, stream>>>(part, stats);
        ln_apply_k<<<8192, 256, 0, stream>>>(ybh, ybl, ffnf,
                                             ln2w + (long)l * SD, ln2b + (long)l * SD,
                                             stats, ybh, ybl, yf16, fdst,
                                             (l == 0) ? wkbq_next : nullptr,
                                             (l == 0) ? vbias : nullptr);
    }
}

// Round 18
// 945.059 us; speedup vs baseline: 1.2069x; 1.0440x over previous
//
#include <hip/hip_runtime.h>
#include <cstdint>
#include <cstddef>

using bf16 = __bf16;
using f16  = _Float16;
typedef float f32x4 __attribute__((ext_vector_type(4)));
typedef bf16 bf16x8 __attribute__((ext_vector_type(8)));
typedef bf16 bf16x4 __attribute__((ext_vector_type(4)));
typedef f16  f16x8  __attribute__((ext_vector_type(8)));
typedef f16  f16x4  __attribute__((ext_vector_type(4)));

#define NB 4           // batch
#define SEQ 2048
#define DM 1024        // d_model
#define HD 4096        // hidden
#define SD (SEQ*DM)    // 2^21 elems per sample

__device__ __forceinline__ float geluf(float v) {
    return 0.5f * v * (1.0f + erff(v * 0.70710678118654752f));
}

#define GLL(gp, lp) __builtin_amdgcn_global_load_lds( \
    (const __attribute__((address_space(1))) void*)(gp), \
    (__attribute__((address_space(3))) void*)(lp), 16, 0, 0)

// ---------------------------------------------------------------------------
// Precision-tiered NT GEMM (proven single-buffer structure + block swizzle):
//   NP=3 (DT=0): C = Ah*Bh + Al*Bh + Ah*Bl  (split bf16, ~17-bit mantissa)
//   NP=1, DT=1 : C = A*B with fp16 operands (10-bit mantissa, 1 pass)
// EPI: 0 = f32 (+bias), 1 = f32 gelu (+bias), 4 = split bf16 store,
//      6 = fp16 store, 7 = fp16 transposed store
// ---------------------------------------------------------------------------
template<int EPI, bool BIAS, int NP, int DT>
__global__ __launch_bounds__(256, NP == 1 ? 4 : 2) void gemm3_nt(
    const bf16* __restrict__ Ah, const bf16* __restrict__ Al,
    const bf16* __restrict__ Bh, const bf16* __restrict__ Bl,
    const float* __restrict__ bias, void* __restrict__ Cg, void* __restrict__ Cl,
    const int K, const int ldab, const int ldc,
    const long sA, const long sB, const long sC)
{
    constexpr int TILE = 128 * 64;                 // elems per plane
    constexpr int LOSZ = (NP == 3) ? TILE : 8;     // lo planes only for NP=3
    __shared__ __align__(16) bf16 smAh[TILE];
    __shared__ __align__(16) bf16 smBh[TILE];
    __shared__ __align__(16) bf16 smAl[LOSZ];
    __shared__ __align__(16) bf16 smBl[LOSZ];

    const int tid  = threadIdx.x;
    const int lane = tid & 63;
    const int wave = tid >> 6;
    const int wr   = (wave >> 1) << 6;
    const int wc   = (wave & 1) << 6;
    const int l15  = lane & 15;
    const int q4   = lane >> 4;

    // ---- block swizzle: XCD chunk + 4x4 output supertile (bijective) ----
    int bx = blockIdx.x, by = blockIdx.y;
    {
        const int gx = gridDim.x, gy = gridDim.y;
        if (((gx & 3) | (gy & 3)) == 0) {
            const int tot = gx * gy;               // multiple of 16
            const int n   = bx + gx * by;
            const int l   = (n & 7) * (tot >> 3) + (n >> 3);   // XCD chunk
            const int st  = l >> 4, pos = l & 15;              // supertile
            bx = (st % (gx >> 2)) * 4 + (pos & 3);
            by = (st / (gx >> 2)) * 4 + (pos >> 2);
        }
    }

    const long aoff = (long)blockIdx.z * sA + (long)bx * 128 * ldab;
    const long boff = (long)blockIdx.z * sB + (long)by * 128 * ldab;
    const bf16* pAh = Ah + aoff;
    const bf16* pAl = (NP == 3) ? Al + aoff : nullptr;
    const bf16* pBh = Bh + boff;
    const bf16* pBl = (NP == 3) ? Bl + boff : nullptr;

    int srow[4], scol[4];
#pragma unroll
    for (int it = 0; it < 4; ++it) {
        int chunk = it * 256 + tid;
        int m = chunk >> 3;
        srow[it] = m;
        scol[it] = ((chunk & 7) ^ (m & 7)) * 8;
    }

    f32x4 acc[4][4] = {};

    for (int k0 = 0; k0 < K; k0 += 64) {
#pragma unroll
        for (int it = 0; it < 4; ++it) {
            const long go = (long)srow[it] * ldab + (k0 + scol[it]);
            const size_t lo = (size_t)(it * 256 + (wave << 6)) * 8;   // linear fill
            GLL(pAh + go, smAh + lo);
            if constexpr (NP == 3) GLL(pAl + go, smAl + lo);
            GLL(pBh + go, smBh + lo);
            if constexpr (NP == 3) GLL(pBl + go, smBl + lo);
        }
        __syncthreads();

#pragma unroll
        for (int kk = 0; kk < 2; ++kk) {
            bf16x8 avh[4], avl[4], bvh[4], bvl[4];
#pragma unroll
            for (int i = 0; i < 4; ++i) {
                const int rowa = wr + i * 16 + l15;
                const int ca = ((kk * 4 + q4) ^ (rowa & 7)) * 8;   // swizzled read
                avh[i] = *(const bf16x8*)(smAh + rowa * 64 + ca);
                if constexpr (NP == 3) avl[i] = *(const bf16x8*)(smAl + rowa * 64 + ca);
                const int rowb = wc + i * 16 + l15;
                const int cb = ((kk * 4 + q4) ^ (rowb & 7)) * 8;
                bvh[i] = *(const bf16x8*)(smBh + rowb * 64 + cb);
                if constexpr (NP == 3) bvl[i] = *(const bf16x8*)(smBl + rowb * 64 + cb);
            }
#pragma unroll
            for (int i = 0; i < 4; ++i)
#pragma unroll
                for (int j = 0; j < 4; ++j) {
                    if constexpr (DT == 1) {
                        acc[i][j] = __builtin_amdgcn_mfma_f32_16x16x32_f16(
                            *(const f16x8*)&avh[i], *(const f16x8*)&bvh[j],
                            acc[i][j], 0, 0, 0);
                    } else {
                        acc[i][j] = __builtin_amdgcn_mfma_f32_16x16x32_bf16(
                            avh[i], bvh[j], acc[i][j], 0, 0, 0);
                        if constexpr (NP == 3) {
                            acc[i][j] = __builtin_amdgcn_mfma_f32_16x16x32_bf16(
                                avl[i], bvh[j], acc[i][j], 0, 0, 0);
                            acc[i][j] = __builtin_amdgcn_mfma_f32_16x16x32_bf16(
                                avh[i], bvl[j], acc[i][j], 0, 0, 0);
                        }
                    }
                }
        }
        __syncthreads();
    }

    // epilogue: D col = lane&15, row = (lane>>4)*4 + e
    const long zC = (long)blockIdx.z * sC;
    const int gcol0 = by * 128 + wc + l15;
    const int grow0 = bx * 128 + wr + q4 * 4;
#pragma unroll
    for (int j = 0; j < 4; ++j) {
        const int col = gcol0 + j * 16;
        const float bvz = BIAS ? bias[col] : 0.0f;
#pragma unroll
        for (int i = 0; i < 4; ++i) {
            const int row = grow0 + i * 16;
            if (EPI == 7) {
                f16x4 o;
#pragma unroll
                for (int e = 0; e < 4; ++e) o[e] = (f16)(acc[i][j][e] + bvz);
                *(f16x4*)((f16*)Cg + zC + (long)col * ldc + row) = o;
            } else {
#pragma unroll
                for (int e = 0; e < 4; ++e) {
                    float v = acc[i][j][e] + bvz;
                    if (EPI == 1) v = geluf(v);
                    const long off = zC + (long)(row + e) * ldc + col;
                    if (EPI == 4) {
                        const bf16 hi = (bf16)v;
                        ((bf16*)Cg)[off] = hi;
                        ((bf16*)Cl)[off] = (bf16)(v - (float)hi);
                    } else if (EPI == 6) {
                        ((f16*)Cg)[off] = (f16)v;
                    } else {
                        ((float*)Cg)[off] = v;
                    }
                }
            }
        }
    }
}

// ---------------------------------------------------------------------------
// y = emb[x] + pos -> split bf16 + fp16 plane; vbias row-dot
// ---------------------------------------------------------------------------
__global__ __launch_bounds__(256) void embed_k(
    const int* __restrict__ x, const float* __restrict__ emb,
    bf16* __restrict__ yh, bf16* __restrict__ yl, f16* __restrict__ yf16,
    const float* __restrict__ wkbq, float* __restrict__ vb)
{
    const int bs = blockIdx.x;          // row
    const int s = bs & (SEQ - 1);
    const long e0 = (long)x[bs] * DM;
    const int d = threadIdx.x * 4;
    const float4 ev = *(const float4*)(emb + e0 + d);
    float o[4];
    const float fs = (float)s;
#pragma unroll
    for (int e = 0; e < 4; ++e) {
        const int dd = d + e;
        const float div = powf(10000.0f, (float)dd * (1.0f / 1024.0f));
        const float ang = fs / div;
        const float p = (dd & 1) ? cosf(ang) : sinf(ang);
        o[e] = ((const float*)&ev)[e] + p;
    }
    bf16x4 oh, ol; f16x4 of;
#pragma unroll
    for (int e = 0; e < 4; ++e) {
        oh[e] = (bf16)o[e];
        ol[e] = (bf16)(o[e] - (float)oh[e]);
        of[e] = (f16)o[e];
    }
    *(bf16x4*)(yh + (long)bs * DM + d) = oh;
    *(bf16x4*)(yl + (long)bs * DM + d) = ol;
    *(f16x4*) (yf16 + (long)bs * DM + d) = of;
    const float4 wv = *(const float4*)(wkbq + d);
    float sdot = o[0] * wv.x + o[1] * wv.y + o[2] * wv.z + o[3] * wv.w;
#pragma unroll
    for (int off = 32; off; off >>= 1) sdot += __shfl_xor(sdot, off);
    __shared__ float red[4];
    if ((threadIdx.x & 63) == 0) red[threadIdx.x >> 6] = sdot;
    __syncthreads();
    if (threadIdx.x == 0) vb[bs] = red[0] + red[1] + red[2] + red[3];
}

// ---------------------------------------------------------------------------
// f32 -> split bf16 straight copy (layer-0 score weights)
// ---------------------------------------------------------------------------
__global__ __launch_bounds__(256) void copy_split_k(
    const float* __restrict__ src, bf16* __restrict__ dh, bf16* __restrict__ dl)
{
    const long i = ((long)blockIdx.x * 256 + threadIdx.x) * 4;
    const float4 v = *(const float4*)(src + i);
    const float vv[4] = {v.x, v.y, v.z, v.w};
    bf16x4 oh, ol;
#pragma unroll
    for (int e = 0; e < 4; ++e) {
        const bf16 hi = (bf16)vv[e];
        oh[e] = hi;
        ol[e] = (bf16)(vv[e] - (float)hi);
    }
    *(bf16x4*)(dh + i) = oh;
    *(bf16x4*)(dl + i) = ol;
}

// ---------------------------------------------------------------------------
// f32 -> f16 straight copy
// ---------------------------------------------------------------------------
__global__ __launch_bounds__(256) void copy_f16_k(
    const float* __restrict__ src, f16* __restrict__ dst)
{
    const long i = ((long)blockIdx.x * 256 + threadIdx.x) * 4;
    const float4 v = *(const float4*)(src + i);
    f16x4 o;
    o[0] = (f16)v.x; o[1] = (f16)v.y; o[2] = (f16)v.z; o[3] = (f16)v.w;
    *(f16x4*)(dst + i) = o;
}

// ---------------------------------------------------------------------------
// f32 R x C -> f16 C x R transpose
// ---------------------------------------------------------------------------
__global__ __launch_bounds__(256) void transpose_f16_k(
    const float* __restrict__ src, f16* __restrict__ dst, int R, int C)
{
    __shared__ f16 tf[64][65];
    const int c0 = blockIdx.x * 64, r0 = blockIdx.y * 64;
    const int t = threadIdx.x;
    const int tr = t >> 4;
    const int tc = (t & 15) * 4;
#pragma unroll
    for (int p = 0; p < 4; ++p) {
        const int r = tr + p * 16;
        const float4 v = *(const float4*)(src + (long)(r0 + r) * C + c0 + tc);
        tf[r][tc] = (f16)v.x; tf[r][tc + 1] = (f16)v.y;
        tf[r][tc + 2] = (f16)v.z; tf[r][tc + 3] = (f16)v.w;
    }
    __syncthreads();
#pragma unroll
    for (int p = 0; p < 4; ++p) {
        const int c = tr + p * 16;
        f16x4 o;
        o[0] = tf[tc][c]; o[1] = tf[tc + 1][c]; o[2] = tf[tc + 2][c]; o[3] = tf[tc + 3][c];
        *(f16x4*)(dst + (long)(c0 + c) * R + r0 + tc) = o;
    }
}

// ---------------------------------------------------------------------------
// 8-plane f32 reduce -> split bf16 (straight, MT layer 0)
// ---------------------------------------------------------------------------
__global__ __launch_bounds__(256) void reduce8s_k(
    const float* __restrict__ p, bf16* __restrict__ dh, bf16* __restrict__ dl)
{
    const long i = ((long)blockIdx.x * 256 + threadIdx.x) * 4;
    const long PL = (long)1 << 20;
    float vv[4] = {0.f, 0.f, 0.f, 0.f};
#pragma unroll
    for (int q = 0; q < 8; ++q) {
        const float4 a = *(const float4*)(p + q * PL + i);
        vv[0] += a.x; vv[1] += a.y; vv[2] += a.z; vv[3] += a.w;
    }
    bf16x4 oh, ol;
#pragma unroll
    for (int e = 0; e < 4; ++e) {
        const bf16 hi = (bf16)vv[e];
        oh[e] = hi;
        ol[e] = (bf16)(vv[e] - (float)hi);
    }
    *(bf16x4*)(dh + i) = oh;
    *(bf16x4*)(dl + i) = ol;
}

// ---------------------------------------------------------------------------
// 8-plane f32 reduce -> f16 (straight, MT layer 1)
// ---------------------------------------------------------------------------
__global__ __launch_bounds__(256) void reduce8sf_k(
    const float* __restrict__ p, f16* __restrict__ df)
{
    const long i = ((long)blockIdx.x * 256 + threadIdx.x) * 4;
    const long PL = (long)1 << 20;
    float vv[4] = {0.f, 0.f, 0.f, 0.f};
#pragma unroll
    for (int q = 0; q < 8; ++q) {
        const float4 a = *(const float4*)(p + q * PL + i);
        vv[0] += a.x; vv[1] += a.y; vv[2] += a.z; vv[3] += a.w;
    }
    f16x4 of;
#pragma unroll
    for (int e = 0; e < 4; ++e) of[e] = (f16)vv[e];
    *(f16x4*)(df + i) = of;
}

// ---------------------------------------------------------------------------
// 8-plane f32 reduce + TRANSPOSE -> f16 (VO and W12, both layers)
// ---------------------------------------------------------------------------
__global__ __launch_bounds__(256) void reduce8tf_k(
    const float* __restrict__ p, f16* __restrict__ dstf)
{
    __shared__ float tf[64][65];
    const long PL = (long)1 << 20;
    const int c0 = blockIdx.x * 64, r0 = blockIdx.y * 64;
    const int t = threadIdx.x;
    const int tr = t >> 4;
    const int tc = (t & 15) * 4;
#pragma unroll
    for (int pp = 0; pp < 4; ++pp) {
        const int r = tr + pp * 16;
        float vv[4] = {0.f, 0.f, 0.f, 0.f};
#pragma unroll
        for (int q = 0; q < 8; ++q) {
            const float4 v = *(const float4*)(p + q * PL + (long)(r0 + r) * 1024 + c0 + tc);
            vv[0] += v.x; vv[1] += v.y; vv[2] += v.z; vv[3] += v.w;
        }
#pragma unroll
        for (int e = 0; e < 4; ++e) tf[r][tc + e] = vv[e];
    }
    __syncthreads();
#pragma unroll
    for (int pp = 0; pp < 4; ++pp) {
        const int c = tr + pp * 16;
        f16x4 of;
#pragma unroll
        for (int e = 0; e < 4; ++e) of[e] = (f16)tf[tc + e][c];
        *(f16x4*)(dstf + (long)(c0 + c) * 1024 + r0 + tc) = of;
    }
}

// ---------------------------------------------------------------------------
// wb[d] = sum_h W[d][h] * b[h]   (f32, W is [1024][4096])
// ---------------------------------------------------------------------------
__global__ __launch_bounds__(256) void matvec_wb_k(
    const float* __restrict__ W, const float* __restrict__ b, float* __restrict__ out)
{
    const int d = blockIdx.x;
    const int t = threadIdx.x;
    float s = 0.f;
    for (int h = t * 4; h < HD; h += 1024) {
        const float4 wv = *(const float4*)(W + (long)d * HD + h);
        const float4 bv = *(const float4*)(b + h);
        s += wv.x * bv.x + wv.y * bv.y + wv.z * bv.z + wv.w * bv.w;
    }
#pragma unroll
    for (int o = 32; o; o >>= 1) s += __shfl_xor(s, o);
    __shared__ float red[4];
    if ((t & 63) == 0) red[t >> 6] = s;
    __syncthreads();
    if (t == 0) out[d] = red[0] + red[1] + red[2] + red[3];
}

// ---------------------------------------------------------------------------
// out[j] = sum_h Btf[j][h] * b[h] + add[j]   (f16 Bt)
// ---------------------------------------------------------------------------
__global__ __launch_bounds__(256) void matvec_btf_k(
    const f16* __restrict__ btf, const float* __restrict__ b,
    const float* __restrict__ add, float* __restrict__ out)
{
    const int j = blockIdx.x;
    const int t = threadIdx.x;
    float s = 0.f;
    for (int h = t * 4; h < HD; h += 1024) {
        const f16x4 hx = *(const f16x4*)(btf + (long)j * HD + h);
        const float4 bv = *(const float4*)(b + h);
        s += (float)hx[0] * bv.x + (float)hx[1] * bv.y
           + (float)hx[2] * bv.z + (float)hx[3] * bv.w;
    }
#pragma unroll
    for (int o = 32; o; o >>= 1) s += __shfl_xor(s, o);
    __shared__ float red[4];
    if ((t & 63) == 0) red[t >> 6] = s;
    __syncthreads();
    if (t == 0) out[j] = red[0] + red[1] + red[2] + red[3] + add[j];
}

// ---------------------------------------------------------------------------
// Row softmax with key-side column bias -> fp16 P
// ---------------------------------------------------------------------------
__global__ __launch_bounds__(256) void softmax_k(
    const float* __restrict__ S, const float* __restrict__ v,
    f16* __restrict__ P)
{
    const long row = blockIdx.x;
    const float4* src = (const float4*)(S + (row << 11));
    const float* vr = v + (long)(row >> 11) * SEQ;
    const int t = threadIdx.x;
    float4 a = src[t], b = src[256 + t];
    const float4 va = *(const float4*)(vr + t * 4);
    const float4 vb = *(const float4*)(vr + 1024 + t * 4);
    a.x += va.x; a.y += va.y; a.z += va.z; a.w += va.w;
    b.x += vb.x; b.y += vb.y; b.z += vb.z; b.w += vb.w;
    float m = fmaxf(fmaxf(fmaxf(a.x, a.y), fmaxf(a.z, a.w)),
                    fmaxf(fmaxf(b.x, b.y), fmaxf(b.z, b.w)));
#pragma unroll
    for (int o = 32; o; o >>= 1) m = fmaxf(m, __shfl_xor(m, o));
    __shared__ float red1[4], red2[4];
    const int wv = t >> 6;
    if ((t & 63) == 0) red1[wv] = m;
    __syncthreads();
    m = fmaxf(fmaxf(red1[0], red1[1]), fmaxf(red1[2], red1[3]));

    a.x = expf(a.x - m); a.y = expf(a.y - m); a.z = expf(a.z - m); a.w = expf(a.w - m);
    b.x = expf(b.x - m); b.y = expf(b.y - m); b.z = expf(b.z - m); b.w = expf(b.w - m);
    float s = a.x + a.y + a.z + a.w + b.x + b.y + b.z + b.w;
#pragma unroll
    for (int o = 32; o; o >>= 1) s += __shfl_xor(s, o);
    if ((t & 63) == 0) red2[wv] = s;
    __syncthreads();
    s = red2[0] + red2[1] + red2[2] + red2[3];
    const float inv = 1.0f / s;

    f16x4 o0, o1;
    o0[0] = (f16)(a.x * inv); o0[1] = (f16)(a.y * inv);
    o0[2] = (f16)(a.z * inv); o0[3] = (f16)(a.w * inv);
    o1[0] = (f16)(b.x * inv); o1[1] = (f16)(b.y * inv);
    o1[2] = (f16)(b.z * inv); o1[3] = (f16)(b.w * inv);
    *(f16x4*)(P + (row << 11) + t * 4) = o0;
    *(f16x4*)(P + (row << 11) + 1024 + t * 4) = o1;
}

// ---------------------------------------------------------------------------
// LayerNorm over whole (S,D) sample; residual carried as split bf16 (hi+lo).
// ---------------------------------------------------------------------------
__global__ __launch_bounds__(256) void ln_stats_k(
    const bf16* __restrict__ yh, const bf16* __restrict__ yl,
    const float* __restrict__ r, float2* __restrict__ part)
{
    const int b = blockIdx.y;
    const long base = (long)b * SD + (long)blockIdx.x * (SD / 64);
    float s = 0.f, q = 0.f;
    for (int i = threadIdx.x; i < (SD / 64) / 4; i += 256) {
        const bf16x4 h = *(const bf16x4*)(yh + base + i * 4);
        const bf16x4 l = *(const bf16x4*)(yl + base + i * 4);
        const float4 c = *(const float4*)(r + base + i * 4);
        const float cc[4] = {c.x, c.y, c.z, c.w};
#pragma unroll
        for (int e = 0; e < 4; ++e) {
            const float xx = (float)h[e] + (float)l[e] + cc[e];
            s += xx; q += xx * xx;
        }
    }
#pragma unroll
    for (int o = 32; o; o >>= 1) { s += __shfl_xor(s, o); q += __shfl_xor(q, o); }
    __shared__ float rs[4], rq[4];
    const int wv = threadIdx.x >> 6;
    if ((threadIdx.x & 63) == 0) { rs[wv] = s; rq[wv] = q; }
    __syncthreads();
    if (threadIdx.x == 0)
        part[b * 64 + blockIdx.x] = make_float2(rs[0] + rs[1] + rs[2] + rs[3],
                                                rq[0] + rq[1] + rq[2] + rq[3]);
}

__global__ void ln_fin_k(const float2* __restrict__ part, float2* __restrict__ stats)
{
    const int b = blockIdx.x;
    const float2 p = part[b * 64 + threadIdx.x];
    float s = p.x, q = p.y;
#pragma unroll
    for (int o = 32; o; o >>= 1) { s += __shfl_xor(s, o); q += __shfl_xor(q, o); }
    if (threadIdx.x == 0) {
        const float inv_n = 1.0f / (float)SD;
        const float mean = s * inv_n;
        const float var = fmaxf(q * inv_n - mean * mean, 0.f);
        stats[b] = make_float2(mean, rsqrtf(var + 1e-5f));
    }
}

// ln_apply: one block per row. Writes split bf16 + fp16 (+f32 out) and
// optionally the NEXT layer's key-side bias dot (vb[row] = dot(o, wkbq)).
__global__ __launch_bounds__(256) void ln_apply_k(
    const bf16* __restrict__ yh_in, const bf16* __restrict__ yl_in,
    const float* __restrict__ r,
    const float* __restrict__ w, const float* __restrict__ bb,
    const float2* __restrict__ stats,
    bf16* __restrict__ yh_out, bf16* __restrict__ yl_out, f16* __restrict__ yf16,
    float* __restrict__ fout,
    const float* __restrict__ wkbq, float* __restrict__ vb)
{
    const long i = (long)blockIdx.x * 1024 + threadIdx.x * 4;
    const int smp = (int)(i >> 21);
    const long sd = i & (SD - 1);
    const float2 st = stats[smp];
    const bf16x4 h = *(const bf16x4*)(yh_in + i);
    const bf16x4 l = *(const bf16x4*)(yl_in + i);
    const float4 c = *(const float4*)(r + i);
    const float4 wv = *(const float4*)(w + sd);
    const float4 bv = *(const float4*)(bb + sd);
    const float cc[4] = {c.x, c.y, c.z, c.w};
    const float ww[4] = {wv.x, wv.y, wv.z, wv.w};
    const float bbx[4] = {bv.x, bv.y, bv.z, bv.w};
    float o[4];
#pragma unroll
    for (int e = 0; e < 4; ++e) {
        const float xx = (float)h[e] + (float)l[e] + cc[e];
        o[e] = (xx - st.x) * st.y * ww[e] + bbx[e];
    }
    bf16x4 oh, ol; f16x4 of;
#pragma unroll
    for (int e = 0; e < 4; ++e) {
        oh[e] = (bf16)o[e];
        ol[e] = (bf16)(o[e] - (float)oh[e]);
        of[e] = (f16)o[e];
    }
    *(bf16x4*)(yh_out + i) = oh;
    *(bf16x4*)(yl_out + i) = ol;
    *(f16x4*) (yf16 + i) = of;
    if (fout != nullptr) *(float4*)(fout + i) = *(float4*)o;
    if (vb != nullptr) {
        const int d = threadIdx.x * 4;
        const float4 kv = *(const float4*)(wkbq + d);
        float sdot = o[0] * kv.x + o[1] * kv.y + o[2] * kv.z + o[3] * kv.w;
#pragma unroll
        for (int off = 32; off; off >>= 1) sdot += __shfl_xor(sdot, off);
        __shared__ float red[4];
        if ((threadIdx.x & 63) == 0) red[threadIdx.x >> 6] = sdot;
        __syncthreads();
        if (threadIdx.x == 0) vb[blockIdx.x] = red[0] + red[1] + red[2] + red[3];
    }
}

// ---------------------------------------------------------------------------
extern "C" void kernel_launch(void* const* d_in, const int* in_sizes, int n_in,
                              void* d_out, int out_size, void* d_ws, size_t ws_size,
                              hipStream_t stream)
{
    (void)in_sizes; (void)n_in; (void)out_size; (void)ws_size;

    const int*   x    = (const int*)  d_in[0];
    const float* emb  = (const float*)d_in[1];
    const float* wq   = (const float*)d_in[2];
    const float* bq   = (const float*)d_in[3];
    const float* wk   = (const float*)d_in[4];
    const float* bk   = (const float*)d_in[5];
    const float* wv   = (const float*)d_in[6];
    const float* bv   = (const float*)d_in[7];
    const float* wo   = (const float*)d_in[8];
    const float* bo   = (const float*)d_in[9];
    const float* w1   = (const float*)d_in[10];
    const float* b1   = (const float*)d_in[11];
    const float* w2   = (const float*)d_in[12];
    const float* b2   = (const float*)d_in[13];
    const float* ln1w = (const float*)d_in[14];
    const float* ln1b = (const float*)d_in[15];
    const float* ln2w = (const float*)d_in[16];
    const float* ln2b = (const float*)d_in[17];
    (void)bk;   // cancels in softmax (row-constant)

    // Workspace — peak ~324 MiB (≤384 proven-safe).
    char* ws = (char*)d_ws;
    const size_t MB = (size_t)1 << 20;
    bf16*   ybh   = (bf16*) (ws);                  //  16 MiB residual hi
    bf16*   ybl   = (bf16*) (ws + 16  * MB);       //  16 MiB residual lo
    f16*    yf16  = (f16*)  (ws + 32  * MB);       //  16 MiB residual fp16
    bf16*   S0h   = (bf16*) (ws + 48  * MB);       //   8 MiB slot A (split hi / f16)
    bf16*   S0l   = (bf16*) (ws + 56  * MB);       //   8 MiB slot B (split lo / f16)
    bf16*   S1h   = (bf16*) (ws + 64  * MB);       //   8 MiB slot C
    bf16*   S1l   = (bf16*) (ws + 72  * MB);       //   8 MiB slot D
    f16*    F0    = (f16*)  (ws + 48  * MB);       //   f16 view of slot A
    f16*    F1    = (f16*)  (ws + 56  * MB);       //   f16 view of slot B
    bf16*   MTh   = (bf16*) (ws + 80  * MB);       //   2 MiB
    bf16*   MTl   = (bf16*) (ws + 82  * MB);       //   2 MiB
    f16*    MTf   = (f16*)  (ws + 84  * MB);       //   2 MiB
    f16*    VOf   = (f16*)  (ws + 90  * MB);       //   2 MiB
    f16*    W12f  = (f16*)  (ws + 92  * MB);       //   2 MiB
    float*  wkbq2 = (float*)(ws + 98  * MB);                // 2 x 4 KiB
    float*  c_vo  = (float*)(ws + 98  * MB + 0x10000);      // 4 KiB
    float*  c_12  = (float*)(ws + 98  * MB + 0x20000);      // 4 KiB
    float*  vbias = (float*)(ws + 98  * MB + 0x30000);      // 32 KiB
    float2* part  = (float2*)(ws + 98 * MB + 0x40000);
    float2* stats = (float2*)(ws + 98 * MB + 0x50000);
    float*  wtmp8 = (float*)(ws + 100 * MB);       //  32 MiB K-split f32 partials
    bf16*   zh    = (bf16*) (ws + 132 * MB);       //  16 MiB z hi [8192][1024]
    bf16*   zl    = (bf16*) (ws + 148 * MB);       //  16 MiB z lo
    f16*    zf    = (f16*)  (ws + 164 * MB);       //  16 MiB z fp16
    f16*    uTf   = (f16*)  (ws + 180 * MB);       //  16 MiB u^T fp16 [4][1024][2048]
    float*  scf   = (float*)(ws + 196 * MB);       //  64 MiB scores f32 [4][2048][2048]
    f16*    Pf    = (f16*)  (ws + 260 * MB);       //  32 MiB probs fp16
    float*  attout= (float*)(ws + 292 * MB);       //  32 MiB f32 [8192][1024]
    float*  ffnf  = attout;

    const long TSZ = (long)DM * HD;

    // both layers' key-side weight-bias vectors (weight-only, precompute)
    matvec_wb_k<<<1024, 256, 0, stream>>>(wk + 0 * TSZ, bq + 0 * HD, wkbq2);
    matvec_wb_k<<<1024, 256, 0, stream>>>(wk + 1 * TSZ, bq + 1 * HD, wkbq2 + 0x4000 / 4);

    embed_k<<<NB * SEQ, 256, 0, stream>>>(x, emb, ybh, ybl, yf16, wkbq2, vbias);

    for (int l = 0; l < 2; ++l) {
        const float* wkbq_next = wkbq2 + 0x4000 / 4;   // layer-1 vector

        // ============ score path ============
        if (l == 0) {
            // strict NP=3 split (doubly softmax-amplified)
            copy_split_k<<<4096, 256, 0, stream>>>(wq + l * TSZ, S0h, S0l);
            copy_split_k<<<4096, 256, 0, stream>>>(wk + l * TSZ, S1h, S1l);
            gemm3_nt<0, false, 3, 0><<<dim3(8, 8, 8), 256, 0, stream>>>(
                S1h, S1l, S0h, S0l, nullptr, wtmp8, nullptr,
                512, HD, 1024, 512, 512, (long)1 << 20);
            reduce8s_k<<<1024, 256, 0, stream>>>(wtmp8, MTh, MTl);
            gemm3_nt<4, false, 3, 0><<<dim3(64, 8, 1), 256, 0, stream>>>(
                ybh, ybl, MTh, MTl, nullptr, zh, zl, DM, DM, DM, 0, 0, 0);
            gemm3_nt<0, false, 3, 0><<<dim3(16, 16, NB), 256, 0, stream>>>(
                zh, zl, ybh, ybl, nullptr, scf, nullptr,
                DM, DM, SEQ, (long)SD, (long)SD, (long)SEQ * SEQ);
        } else {
            // relaxed fp16 (feeds output only): fp16 K-split product, fp16 GEMMs
            copy_f16_k<<<4096, 256, 0, stream>>>(wq + l * TSZ, F0);
            copy_f16_k<<<4096, 256, 0, stream>>>(wk + l * TSZ, F1);
            gemm3_nt<0, false, 1, 1><<<dim3(8, 8, 8), 256, 0, stream>>>(
                (const bf16*)F1, nullptr, (const bf16*)F0, nullptr, nullptr,
                wtmp8, nullptr, 512, HD, 1024, 512, 512, (long)1 << 20);
            reduce8sf_k<<<1024, 256, 0, stream>>>(wtmp8, MTf);
            gemm3_nt<6, false, 1, 1><<<dim3(64, 8, 1), 256, 0, stream>>>(
                (const bf16*)yf16, nullptr, (const bf16*)MTf, nullptr, nullptr,
                zf, nullptr, DM, DM, DM, 0, 0, 0);
            gemm3_nt<0, false, 1, 1><<<dim3(16, 16, NB), 256, 0, stream>>>(
                (const bf16*)zf, nullptr, (const bf16*)yf16, nullptr, nullptr,
                scf, nullptr, DM, DM, SEQ, (long)SD, (long)SD, (long)SEQ * SEQ);
        }
        softmax_k<<<NB * SEQ, 256, 0, stream>>>(scf, vbias, Pf);

        // ============ value path: W_vo = Wv·Wo (fp16, K-split geometry;
        // precision set == R15 which measured absmax 0.0625) ============
        copy_f16_k     <<<4096, 256, 0, stream>>>(wv + l * TSZ, F0);
        transpose_f16_k<<<dim3(16, 64), 256, 0, stream>>>(wo + l * TSZ, F1, HD, DM);
        matvec_btf_k<<<1024, 256, 0, stream>>>(F1, bv + l * HD, bo + l * DM, c_vo);
        gemm3_nt<0, false, 1, 1><<<dim3(8, 8, 8), 256, 0, stream>>>(
            (const bf16*)F0, nullptr, (const bf16*)F1, nullptr, nullptr,
            wtmp8, nullptr, 512, HD, 1024, 512, 512, (long)1 << 20);
        reduce8tf_k<<<dim3(16, 16), 256, 0, stream>>>(wtmp8, VOf);
        // u^T = (y·W_vo)^T -> fp16 [4][1024][2048]
        gemm3_nt<7, false, 1, 1><<<dim3(16, 8, NB), 256, 0, stream>>>(
            (const bf16*)yf16, nullptr, (const bf16*)VOf, nullptr, nullptr,
            uTf, nullptr, DM, DM, SEQ, (long)SD, 0, (long)DM * SEQ);
        // attout = P·u + c_vo (fp16 NP=1 both layers)
        gemm3_nt<0, true, 1, 1><<<dim3(16, 8, NB), 256, 0, stream>>>(
            (const bf16*)Pf, nullptr, (const bf16*)uTf, nullptr, c_vo, attout, nullptr,
            SEQ, SEQ, DM, (long)SEQ * SEQ, (long)DM * SEQ, (long)SEQ * DM);
        // LN1(y + attout)
        ln_stats_k<<<dim3(64, NB), 256, 0, stream>>>(ybh, ybl, attout, part);
        ln_fin_k  <<<NB, 64, 0, stream>>>(part, stats);
        ln_apply_k<<<8192, 256, 0, stream>>>(ybh, ybl, attout,
                                             ln1w + (long)l * SD, ln1b + (long)l * SD,
                                             stats, ybh, ybl, yf16, nullptr,
                                             nullptr, nullptr);

        // ============ FFN path: W_12 = W1·W2 (exact collapse, fp16) ============
        copy_f16_k     <<<4096, 256, 0, stream>>>(w1 + l * TSZ, F0);
        transpose_f16_k<<<dim3(16, 64), 256, 0, stream>>>(w2 + l * TSZ, F1, HD, DM);
        matvec_btf_k<<<1024, 256, 0, stream>>>(F1, b1 + l * HD, b2 + l * DM, c_12);
        gemm3_nt<0, false, 1, 1><<<dim3(8, 8, 8), 256, 0, stream>>>(
            (const bf16*)F0, nullptr, (const bf16*)F1, nullptr, nullptr,
            wtmp8, nullptr, 512, HD, 1024, 512, 512, (long)1 << 20);
        reduce8tf_k<<<dim3(16, 16), 256, 0, stream>>>(wtmp8, W12f);
        // ffn = gelu(y·W_12 + c_12) (fp16 NP=1)
        gemm3_nt<1, true, 1, 1><<<dim3(64, 8, 1), 256, 0, stream>>>(
            (const bf16*)yf16, nullptr, (const bf16*)W12f, nullptr, c_12,
            ffnf, nullptr, DM, DM, DM, 0, 0, 0);
        // LN2; layer-0 apply also emits next layer's vbias; layer-1 writes d_out
        float* fdst = (l == 1) ? (float*)d_out : nullptr;
        ln_stats_k<<<dim3(64, NB), 256, 0, stream>>>(ybh, ybl, ffnf, part);
        ln_fin_k  <<<NB, 64, 0, stream>>>(part, stats);
        ln_apply_k<<<8192, 256, 0, stream>>>(ybh, ybl, ffnf,
                                             ln2w + (long)l * SD, ln2b + (long)l * SD,
                                             stats, ybh, ybl, yf16, fdst,
                                             (l == 0) ? wkbq_next : nullptr,
                                             (l == 0) ? vbias : nullptr);
    }
}